// Round 1
// baseline (542.807 us; speedup 1.0000x reference)
//
#include <hip/hip_runtime.h>
#include <hip/hip_bf16.h>

// Problem constants (fixed by reference setup_inputs)
constexpr int B_ = 4, C_ = 512, N_ = 4096, NH_ = 8, HD_ = 64;
constexpr int Wimg = 64;            // H=W=64
constexpr int NK = 1024;            // (64/2)*(64/2)
constexpr float SCALE = 0.125f;     // HD^-0.5
constexpr float EPS = 1e-5f;

// ---------------------------------------------------------------------------
// v[b,c] = mean_n x[b,c,n]
__global__ void k_vmean(const float* __restrict__ x, float* __restrict__ v) {
    int bc = blockIdx.x;  // b*C + c
    const float4* row = reinterpret_cast<const float4*>(x + (size_t)bc * N_);
    float s = 0.f;
    for (int i = threadIdx.x; i < N_ / 4; i += 256) {
        float4 f = row[i];
        s += f.x + f.y + f.z + f.w;
    }
    for (int m = 32; m; m >>= 1) s += __shfl_xor(s, m);
    __shared__ float red[4];
    int lane = threadIdx.x & 63, w = threadIdx.x >> 6;
    if (lane == 0) red[w] = s;
    __syncthreads();
    if (threadIdx.x == 0) v[bc] = (red[0] + red[1] + red[2] + red[3]) * (1.0f / N_);
}

// pv[b,o] = sum_c Wproj[o,c] * v[b,c]   (one wave per output)
__global__ void k_pv(const float* __restrict__ Wproj, const float* __restrict__ v,
                     float* __restrict__ pv) {
    int idx = blockIdx.x * 4 + (threadIdx.x >> 6);  // b*C + o
    int lane = threadIdx.x & 63;
    int b = idx / C_, o = idx % C_;
    float s = 0.f;
    for (int c = lane; c < C_; c += 64) s += Wproj[o * C_ + c] * v[b * C_ + c];
    for (int m = 32; m; m >>= 1) s += __shfl_xor(s, m);
    if (lane == 0) pv[idx] = s;
}

// ---------------------------------------------------------------------------
// q2[b,o,n] = sum_c Wq[o,c] * x[b,c,n]   -> bf16 out (B,C,N)
__global__ __launch_bounds__(256) void k_qgemm(const float* __restrict__ Wq,
                                               const float* __restrict__ x,
                                               __hip_bfloat16* __restrict__ q2) {
    const int b = blockIdx.z;
    const int m0 = blockIdx.y * 64;  // o
    const int n0 = blockIdx.x * 64;  // n
    __shared__ float As[16][68];
    __shared__ float Bs[16][64];
    const int tid = threadIdx.x, tx = tid & 15, ty = tid >> 4;
    float acc[4][4] = {};
    const float* xb = x + (size_t)b * C_ * N_;
    for (int k0 = 0; k0 < C_; k0 += 16) {
        {
            int mm = tid >> 2, kk = (tid & 3) * 4;
            float4 a = *reinterpret_cast<const float4*>(&Wq[(size_t)(m0 + mm) * C_ + k0 + kk]);
            As[kk + 0][mm] = a.x; As[kk + 1][mm] = a.y;
            As[kk + 2][mm] = a.z; As[kk + 3][mm] = a.w;
            int kk2 = tid >> 4, nn = (tid & 15) * 4;
            *reinterpret_cast<float4*>(&Bs[kk2][nn]) =
                *reinterpret_cast<const float4*>(&xb[(size_t)(k0 + kk2) * N_ + n0 + nn]);
        }
        __syncthreads();
#pragma unroll
        for (int k = 0; k < 16; ++k) {
            float4 av = *reinterpret_cast<const float4*>(&As[k][ty * 4]);
            float4 bv = *reinterpret_cast<const float4*>(&Bs[k][tx * 4]);
            float a[4] = {av.x, av.y, av.z, av.w}, bb[4] = {bv.x, bv.y, bv.z, bv.w};
#pragma unroll
            for (int i = 0; i < 4; ++i)
#pragma unroll
                for (int j = 0; j < 4; ++j) acc[i][j] += a[i] * bb[j];
        }
        __syncthreads();
    }
    __hip_bfloat16* qb = q2 + (size_t)b * C_ * N_;
#pragma unroll
    for (int i = 0; i < 4; ++i) {
        int o = m0 + ty * 4 + i;
#pragma unroll
        for (int j = 0; j < 4; ++j)
            qb[(size_t)o * N_ + n0 + tx * 4 + j] = __float2bfloat16(acc[i][j]);
    }
}

// ---------------------------------------------------------------------------
// conv 2x2 stride 2 + bias + BN(inference) as im2col GEMM, K = C*4 = 2048
// xsr[b,c,p] fp32
__global__ __launch_bounds__(256) void k_conv(const float* __restrict__ Wsr,
                                              const float* __restrict__ x,
                                              const float* __restrict__ bsr,
                                              const float* __restrict__ gamma,
                                              const float* __restrict__ beta,
                                              const float* __restrict__ mean,
                                              const float* __restrict__ var,
                                              float* __restrict__ xsr) {
    const int b = blockIdx.z;
    const int m0 = blockIdx.y * 64;  // co
    const int p0 = blockIdx.x * 64;  // p = oy*32+ox
    __shared__ float As[16][68];
    __shared__ float Bs[16][64];
    const int tid = threadIdx.x, tx = tid & 15, ty = tid >> 4;
    float acc[4][4] = {};
    const float* xb = x + (size_t)b * C_ * N_;
    for (int k0 = 0; k0 < 2048; k0 += 16) {
        {
            int mm = tid >> 2, kk = (tid & 3) * 4;
            float4 a = *reinterpret_cast<const float4*>(&Wsr[(size_t)(m0 + mm) * 2048 + k0 + kk]);
            As[kk + 0][mm] = a.x; As[kk + 1][mm] = a.y;
            As[kk + 2][mm] = a.z; As[kk + 3][mm] = a.w;
            int kk2 = tid >> 4;
            int k = k0 + kk2;
            int ci = k >> 2, dy = (k >> 1) & 1, dx = k & 1;
            const float* src = xb + (size_t)ci * N_ + dy * Wimg + dx;
            int pp = (tid & 15) * 4;
#pragma unroll
            for (int j = 0; j < 4; ++j) {
                int p = p0 + pp + j;
                int oy = p >> 5, ox = p & 31;
                Bs[kk2][pp + j] = src[oy * 2 * Wimg + ox * 2];
            }
        }
        __syncthreads();
#pragma unroll
        for (int k = 0; k < 16; ++k) {
            float4 av = *reinterpret_cast<const float4*>(&As[k][ty * 4]);
            float4 bv = *reinterpret_cast<const float4*>(&Bs[k][tx * 4]);
            float a[4] = {av.x, av.y, av.z, av.w}, bb[4] = {bv.x, bv.y, bv.z, bv.w};
#pragma unroll
            for (int i = 0; i < 4; ++i)
#pragma unroll
                for (int j = 0; j < 4; ++j) acc[i][j] += a[i] * bb[j];
        }
        __syncthreads();
    }
    float* xsb = xsr + (size_t)b * C_ * NK;
#pragma unroll
    for (int i = 0; i < 4; ++i) {
        int c = m0 + ty * 4 + i;
        float a = rsqrtf(var[c] + EPS) * gamma[c];
        float b2 = (bsr[c] - mean[c]) * a + beta[c];
#pragma unroll
        for (int j = 0; j < 4; ++j)
            xsb[(size_t)c * NK + p0 + tx * 4 + j] = acc[i][j] * a + b2;
    }
}

// ---------------------------------------------------------------------------
// k3[b,o,p] = sum_c Wk[o,c] * xsr[b,c,p]   fp32 out (B,C,NK)
__global__ __launch_bounds__(256) void k_kgemm(const float* __restrict__ Wk,
                                               const float* __restrict__ xsr,
                                               float* __restrict__ k3) {
    const int b = blockIdx.z;
    const int m0 = blockIdx.y * 64;  // o
    const int p0 = blockIdx.x * 64;  // p
    __shared__ float As[16][68];
    __shared__ float Bs[16][64];
    const int tid = threadIdx.x, tx = tid & 15, ty = tid >> 4;
    float acc[4][4] = {};
    const float* xsb = xsr + (size_t)b * C_ * NK;
    for (int k0 = 0; k0 < C_; k0 += 16) {
        {
            int mm = tid >> 2, kk = (tid & 3) * 4;
            float4 a = *reinterpret_cast<const float4*>(&Wk[(size_t)(m0 + mm) * C_ + k0 + kk]);
            As[kk + 0][mm] = a.x; As[kk + 1][mm] = a.y;
            As[kk + 2][mm] = a.z; As[kk + 3][mm] = a.w;
            int kk2 = tid >> 4, nn = (tid & 15) * 4;
            *reinterpret_cast<float4*>(&Bs[kk2][nn]) =
                *reinterpret_cast<const float4*>(&xsb[(size_t)(k0 + kk2) * NK + p0 + nn]);
        }
        __syncthreads();
#pragma unroll
        for (int k = 0; k < 16; ++k) {
            float4 av = *reinterpret_cast<const float4*>(&As[k][ty * 4]);
            float4 bv = *reinterpret_cast<const float4*>(&Bs[k][tx * 4]);
            float a[4] = {av.x, av.y, av.z, av.w}, bb[4] = {bv.x, bv.y, bv.z, bv.w};
#pragma unroll
            for (int i = 0; i < 4; ++i)
#pragma unroll
                for (int j = 0; j < 4; ++j) acc[i][j] += a[i] * bb[j];
        }
        __syncthreads();
    }
    float* kb = k3 + (size_t)b * C_ * NK;
#pragma unroll
    for (int i = 0; i < 4; ++i) {
        int o = m0 + ty * 4 + i;
#pragma unroll
        for (int j = 0; j < 4; ++j)
            kb[(size_t)o * NK + p0 + tx * 4 + j] = acc[i][j];
    }
}

// ---------------------------------------------------------------------------
// attention: am[b,h,n] = max_p sum_d q[b,h,n,d]*k[b,h,d,p]  (scale applied after max)
// block = 64 n-rows for one (b,h); loops over all 1024 p in 16 tiles of 64
__global__ __launch_bounds__(256) void k_attn(const __hip_bfloat16* __restrict__ q2,
                                              const float* __restrict__ k3,
                                              float* __restrict__ am) {
    const int b = blockIdx.z, h = blockIdx.y;
    const int n0 = blockIdx.x * 64;
    __shared__ float As[64][68];  // [d][n]
    __shared__ float Bs[64][68];  // [d][p]
    const int tid = threadIdx.x, tx = tid & 15, ty = tid >> 4;

    const __hip_bfloat16* qb = q2 + ((size_t)b * C_ + h * HD_) * N_;
    {
        int d = tid >> 2, nn = (tid & 3) * 16;
#pragma unroll
        for (int j = 0; j < 16; ++j)
            As[d][nn + j] = __bfloat162float(qb[(size_t)d * N_ + n0 + nn + j]);
    }
    const float* kb = k3 + ((size_t)b * C_ + h * HD_) * NK;

    float rmax[4];
#pragma unroll
    for (int i = 0; i < 4; ++i) rmax[i] = -3.4e38f;

    for (int pt = 0; pt < 16; ++pt) {
        __syncthreads();  // also makes As visible on first iteration
        {
            int d = tid >> 2, pp = (tid & 3) * 16;
            const float* src = &kb[(size_t)d * NK + pt * 64 + pp];
#pragma unroll
            for (int j = 0; j < 4; ++j)
                *reinterpret_cast<float4*>(&Bs[d][pp + j * 4]) =
                    *reinterpret_cast<const float4*>(&src[j * 4]);
        }
        __syncthreads();
        float acc[4][4] = {};
#pragma unroll 8
        for (int k = 0; k < 64; ++k) {
            float4 av = *reinterpret_cast<const float4*>(&As[k][ty * 4]);
            float4 bv = *reinterpret_cast<const float4*>(&Bs[k][tx * 4]);
            float a[4] = {av.x, av.y, av.z, av.w}, bb[4] = {bv.x, bv.y, bv.z, bv.w};
#pragma unroll
            for (int i = 0; i < 4; ++i)
#pragma unroll
                for (int j = 0; j < 4; ++j) acc[i][j] += a[i] * bb[j];
        }
#pragma unroll
        for (int i = 0; i < 4; ++i) {
            float m = fmaxf(fmaxf(acc[i][0], acc[i][1]), fmaxf(acc[i][2], acc[i][3]));
            rmax[i] = fmaxf(rmax[i], m);
        }
    }
#pragma unroll
    for (int i = 0; i < 4; ++i) {
        float m = rmax[i];
        for (int s = 1; s < 16; s <<= 1) m = fmaxf(m, __shfl_xor(m, s));
        rmax[i] = m;
    }
    if (tx == 0) {
        float* amp = am + ((size_t)(b * NH_ + h)) * N_ + n0;
#pragma unroll
        for (int i = 0; i < 4; ++i) amp[ty * 4 + i] = SCALE * rmax[i];
    }
}

// ---------------------------------------------------------------------------
// out[b,o,n] = pv[b,o] * (sum_h am[b,h,n]) + bproj[o]
__global__ void k_final(const float* __restrict__ pv, const float* __restrict__ am,
                        const float* __restrict__ bproj, float* __restrict__ out) {
    int b = blockIdx.y;
    int n = blockIdx.x * 256 + threadIdx.x;
    float s = 0.f;
#pragma unroll
    for (int h = 0; h < NH_; ++h) s += am[((size_t)b * NH_ + h) * N_ + n];
    const float* pvb = pv + b * C_;
    float* ob = out + (size_t)b * C_ * N_ + n;
    for (int o = 0; o < C_; ++o) ob[(size_t)o * N_] = pvb[o] * s + bproj[o];
}

// ---------------------------------------------------------------------------
extern "C" void kernel_launch(void* const* d_in, const int* in_sizes, int n_in,
                              void* d_out, int out_size, void* d_ws, size_t ws_size,
                              hipStream_t stream) {
    const float* x     = (const float*)d_in[0];
    // d_in[1] = y (unused by forward)
    const float* Wq    = (const float*)d_in[2];
    const float* Wk    = (const float*)d_in[3];
    const float* Wsr   = (const float*)d_in[4];
    const float* bsr   = (const float*)d_in[5];
    const float* gamma = (const float*)d_in[6];
    const float* beta  = (const float*)d_in[7];
    const float* mean  = (const float*)d_in[8];
    const float* var   = (const float*)d_in[9];
    const float* Wproj = (const float*)d_in[10];
    const float* bproj = (const float*)d_in[11];
    float* out = (float*)d_out;

    char* ws = (char*)d_ws;
    // workspace layout (33.6 MB total)
    float*          v   = (float*)(ws);                                  // 8 KB
    float*          pv  = (float*)(ws + 8192);                           // 8 KB
    __hip_bfloat16* q2  = (__hip_bfloat16*)(ws + 16384);                 // 16 MB
    float*          xsr = (float*)(ws + 16384 + 16777216);               // 8 MB
    float*          k3  = (float*)(ws + 16384 + 16777216 + 8388608);     // 8 MB
    float*          am  = (float*)(ws + 16384 + 16777216 + 2 * 8388608); // 512 KB

    k_vmean<<<dim3(B_ * C_), 256, 0, stream>>>(x, v);
    k_pv<<<dim3(B_ * C_ / 4), 256, 0, stream>>>(Wproj, v, pv);
    k_qgemm<<<dim3(N_ / 64, C_ / 64, B_), 256, 0, stream>>>(Wq, x, q2);
    k_conv<<<dim3(NK / 64, C_ / 64, B_), 256, 0, stream>>>(Wsr, x, bsr, gamma, beta, mean, var, xsr);
    k_kgemm<<<dim3(NK / 64, C_ / 64, B_), 256, 0, stream>>>(Wk, xsr, k3);
    k_attn<<<dim3(N_ / 64, NH_, B_), 256, 0, stream>>>(q2, k3, am);
    k_final<<<dim3(N_ / 256, B_), 256, 0, stream>>>(pv, am, bproj, out);
}

// Round 2
// 377.843 us; speedup vs baseline: 1.4366x; 1.4366x over previous
//
#include <hip/hip_runtime.h>
#include <hip/hip_bf16.h>

// Problem constants (fixed by reference setup_inputs)
constexpr int B_ = 4, C_ = 512, N_ = 4096, NH_ = 8, HD_ = 64;
constexpr int Wimg = 64;            // H=W=64
constexpr int NK = 1024;            // (64/2)*(64/2)
constexpr float SCALE = 0.125f;     // HD^-0.5
constexpr float EPS = 1e-5f;

typedef __attribute__((ext_vector_type(8))) short bf16x8;
typedef __attribute__((ext_vector_type(4))) float f32x4;

// ---------------------------------------------------------------------------
// v[b,c] = mean_n x[b,c,n]
__global__ void k_vmean(const float* __restrict__ x, float* __restrict__ v) {
    int bc = blockIdx.x;  // b*C + c
    const float4* row = reinterpret_cast<const float4*>(x + (size_t)bc * N_);
    float s = 0.f;
    for (int i = threadIdx.x; i < N_ / 4; i += 256) {
        float4 f = row[i];
        s += f.x + f.y + f.z + f.w;
    }
    for (int m = 32; m; m >>= 1) s += __shfl_xor(s, m);
    __shared__ float red[4];
    int lane = threadIdx.x & 63, w = threadIdx.x >> 6;
    if (lane == 0) red[w] = s;
    __syncthreads();
    if (threadIdx.x == 0) v[bc] = (red[0] + red[1] + red[2] + red[3]) * (1.0f / N_);
}

// pv[b,o] = sum_c Wproj[o,c] * v[b,c]   (one wave per output)
__global__ void k_pv(const float* __restrict__ Wproj, const float* __restrict__ v,
                     float* __restrict__ pv) {
    int idx = blockIdx.x * 4 + (threadIdx.x >> 6);  // b*C + o
    int lane = threadIdx.x & 63;
    int b = idx / C_, o = idx % C_;
    float s = 0.f;
    for (int c = lane; c < C_; c += 64) s += Wproj[o * C_ + c] * v[b * C_ + c];
    for (int m = 32; m; m >>= 1) s += __shfl_xor(s, m);
    if (lane == 0) pv[idx] = s;
}

// ---------------------------------------------------------------------------
// q[b,h,n,d] = sum_c Wq[h*64+d,c] * x[b,c,n]   -> bf16, d-contiguous
__global__ __launch_bounds__(256) void k_qgemm(const float* __restrict__ Wq,
                                               const float* __restrict__ x,
                                               __hip_bfloat16* __restrict__ q2) {
    const int b = blockIdx.z;
    const int m0 = blockIdx.y * 64;  // o = h*64+d ; m0 64-aligned -> h = m0>>6
    const int n0 = blockIdx.x * 64;  // n
    __shared__ float As[16][68];
    __shared__ float Bs[16][64];
    const int tid = threadIdx.x, tx = tid & 15, ty = tid >> 4;
    float acc[4][4] = {};
    const float* xb = x + (size_t)b * C_ * N_;
    for (int k0 = 0; k0 < C_; k0 += 16) {
        {
            int mm = tid >> 2, kk = (tid & 3) * 4;
            float4 a = *reinterpret_cast<const float4*>(&Wq[(size_t)(m0 + mm) * C_ + k0 + kk]);
            As[kk + 0][mm] = a.x; As[kk + 1][mm] = a.y;
            As[kk + 2][mm] = a.z; As[kk + 3][mm] = a.w;
            int kk2 = tid >> 4, nn = (tid & 15) * 4;
            *reinterpret_cast<float4*>(&Bs[kk2][nn]) =
                *reinterpret_cast<const float4*>(&xb[(size_t)(k0 + kk2) * N_ + n0 + nn]);
        }
        __syncthreads();
#pragma unroll
        for (int k = 0; k < 16; ++k) {
            float4 av = *reinterpret_cast<const float4*>(&As[k][ty * 4]);
            float4 bv = *reinterpret_cast<const float4*>(&Bs[k][tx * 4]);
            float a[4] = {av.x, av.y, av.z, av.w}, bb[4] = {bv.x, bv.y, bv.z, bv.w};
#pragma unroll
            for (int i = 0; i < 4; ++i)
#pragma unroll
                for (int j = 0; j < 4; ++j) acc[i][j] += a[i] * bb[j];
        }
        __syncthreads();
    }
    // write [b,h,n,d]: d = ty*4+i (m0 is 64-aligned), h = m0>>6
    __hip_bfloat16* qb = q2 + (size_t)(b * NH_ + (m0 >> 6)) * N_ * HD_;
#pragma unroll
    for (int j = 0; j < 4; ++j) {
        union { short4 s; __hip_bfloat16 h[4]; } u;
#pragma unroll
        for (int i = 0; i < 4; ++i) u.h[i] = __float2bfloat16(acc[i][j]);
        *reinterpret_cast<short4*>(&qb[(size_t)(n0 + tx * 4 + j) * HD_ + ty * 4]) = u.s;
    }
}

// ---------------------------------------------------------------------------
// conv 2x2 stride 2 + bias + BN(inference) as im2col GEMM, K = C*4 = 2048
// xsr[b,c,p] fp32
__global__ __launch_bounds__(256) void k_conv(const float* __restrict__ Wsr,
                                              const float* __restrict__ x,
                                              const float* __restrict__ bsr,
                                              const float* __restrict__ gamma,
                                              const float* __restrict__ beta,
                                              const float* __restrict__ mean,
                                              const float* __restrict__ var,
                                              float* __restrict__ xsr) {
    const int b = blockIdx.z;
    const int m0 = blockIdx.y * 64;  // co
    const int p0 = blockIdx.x * 64;  // p = oy*32+ox
    __shared__ float As[16][68];
    __shared__ float Bs[16][64];
    const int tid = threadIdx.x, tx = tid & 15, ty = tid >> 4;
    float acc[4][4] = {};
    const float* xb = x + (size_t)b * C_ * N_;
    for (int k0 = 0; k0 < 2048; k0 += 16) {
        {
            int mm = tid >> 2, kk = (tid & 3) * 4;
            float4 a = *reinterpret_cast<const float4*>(&Wsr[(size_t)(m0 + mm) * 2048 + k0 + kk]);
            As[kk + 0][mm] = a.x; As[kk + 1][mm] = a.y;
            As[kk + 2][mm] = a.z; As[kk + 3][mm] = a.w;
            int kk2 = tid >> 4;
            int k = k0 + kk2;
            int ci = k >> 2, dy = (k >> 1) & 1, dx = k & 1;
            const float* src = xb + (size_t)ci * N_ + dy * Wimg + dx;
            int pp = (tid & 15) * 4;
#pragma unroll
            for (int j = 0; j < 4; ++j) {
                int p = p0 + pp + j;
                int oy = p >> 5, ox = p & 31;
                Bs[kk2][pp + j] = src[oy * 2 * Wimg + ox * 2];
            }
        }
        __syncthreads();
#pragma unroll
        for (int k = 0; k < 16; ++k) {
            float4 av = *reinterpret_cast<const float4*>(&As[k][ty * 4]);
            float4 bv = *reinterpret_cast<const float4*>(&Bs[k][tx * 4]);
            float a[4] = {av.x, av.y, av.z, av.w}, bb[4] = {bv.x, bv.y, bv.z, bv.w};
#pragma unroll
            for (int i = 0; i < 4; ++i)
#pragma unroll
                for (int j = 0; j < 4; ++j) acc[i][j] += a[i] * bb[j];
        }
        __syncthreads();
    }
    float* xsb = xsr + (size_t)b * C_ * NK;
#pragma unroll
    for (int i = 0; i < 4; ++i) {
        int c = m0 + ty * 4 + i;
        float a = rsqrtf(var[c] + EPS) * gamma[c];
        float b2 = (bsr[c] - mean[c]) * a + beta[c];
#pragma unroll
        for (int j = 0; j < 4; ++j)
            xsb[(size_t)c * NK + p0 + tx * 4 + j] = acc[i][j] * a + b2;
    }
}

// ---------------------------------------------------------------------------
// k[b,h,p,d] = sum_c Wk[h*64+d,c] * xsr[b,c,p]   -> bf16, d-contiguous
__global__ __launch_bounds__(256) void k_kgemm(const float* __restrict__ Wk,
                                               const float* __restrict__ xsr,
                                               __hip_bfloat16* __restrict__ k3) {
    const int b = blockIdx.z;
    const int m0 = blockIdx.y * 64;  // o = h*64+d
    const int p0 = blockIdx.x * 64;  // p
    __shared__ float As[16][68];
    __shared__ float Bs[16][64];
    const int tid = threadIdx.x, tx = tid & 15, ty = tid >> 4;
    float acc[4][4] = {};
    const float* xsb = xsr + (size_t)b * C_ * NK;
    for (int k0 = 0; k0 < C_; k0 += 16) {
        {
            int mm = tid >> 2, kk = (tid & 3) * 4;
            float4 a = *reinterpret_cast<const float4*>(&Wk[(size_t)(m0 + mm) * C_ + k0 + kk]);
            As[kk + 0][mm] = a.x; As[kk + 1][mm] = a.y;
            As[kk + 2][mm] = a.z; As[kk + 3][mm] = a.w;
            int kk2 = tid >> 4, nn = (tid & 15) * 4;
            *reinterpret_cast<float4*>(&Bs[kk2][nn]) =
                *reinterpret_cast<const float4*>(&xsb[(size_t)(k0 + kk2) * NK + p0 + nn]);
        }
        __syncthreads();
#pragma unroll
        for (int k = 0; k < 16; ++k) {
            float4 av = *reinterpret_cast<const float4*>(&As[k][ty * 4]);
            float4 bv = *reinterpret_cast<const float4*>(&Bs[k][tx * 4]);
            float a[4] = {av.x, av.y, av.z, av.w}, bb[4] = {bv.x, bv.y, bv.z, bv.w};
#pragma unroll
            for (int i = 0; i < 4; ++i)
#pragma unroll
                for (int j = 0; j < 4; ++j) acc[i][j] += a[i] * bb[j];
        }
        __syncthreads();
    }
    // write [b,h,p,d]: d = ty*4+i, h = m0>>6
    __hip_bfloat16* kb = k3 + (size_t)(b * NH_ + (m0 >> 6)) * NK * HD_;
#pragma unroll
    for (int j = 0; j < 4; ++j) {
        union { short4 s; __hip_bfloat16 h[4]; } u;
#pragma unroll
        for (int i = 0; i < 4; ++i) u.h[i] = __float2bfloat16(acc[i][j]);
        *reinterpret_cast<short4*>(&kb[(size_t)(p0 + tx * 4 + j) * HD_ + ty * 4]) = u.s;
    }
}

// ---------------------------------------------------------------------------
// MFMA attention: am[b,h,n] = SCALE * max_p sum_d q[b,h,n,d]*k[b,h,p,d]
// block = 4 waves sharing one 64-row q tile; waves split the 1024 keys
// (16 p-tiles of 16 each); LDS max-combine at the end.
// A/B frags use the SAME slot->d mapping (d = ks*32 + (lane>>4)*8 + j), so any
// internal MFMA k-permutation cancels; C/D layout: col=lane&15, row=(lane>>4)*4+r.
__global__ __launch_bounds__(256) void k_attn_mfma(const short* __restrict__ q2,
                                                   const short* __restrict__ k3,
                                                   float* __restrict__ am) {
    const int b = blockIdx.z, h = blockIdx.y;
    const int wave = threadIdx.x >> 6, lane = threadIdx.x & 63;
    const int lr = lane & 15, lg = lane >> 4;
    const int n0 = blockIdx.x * 64;

    const short* qb = q2 + (size_t)(b * NH_ + h) * N_ * HD_;
    const short* kb = k3 + (size_t)(b * NH_ + h) * NK * HD_;

    // q tile (64 rows x 64 d) in registers, shared rows across waves
    bf16x8 a[4][2];
#pragma unroll
    for (int mt = 0; mt < 4; ++mt)
#pragma unroll
        for (int ks = 0; ks < 2; ++ks)
            a[mt][ks] = *reinterpret_cast<const bf16x8*>(
                qb + (size_t)(n0 + mt * 16 + lr) * HD_ + ks * 32 + lg * 8);

    float rmax[4][4];
#pragma unroll
    for (int mt = 0; mt < 4; ++mt)
#pragma unroll
        for (int r = 0; r < 4; ++r) rmax[mt][r] = -3.4e38f;

    // this wave's 16 p-tiles: p = (wave*16 + t)*16 + lr
    const short* kwb = kb + (size_t)wave * 16 * 16 * HD_;
    const short* src0 = kwb + (size_t)lr * HD_ + lg * 8;
    bf16x8 nb0 = *reinterpret_cast<const bf16x8*>(src0);
    bf16x8 nb1 = *reinterpret_cast<const bf16x8*>(src0 + 32);
    for (int t = 0; t < 16; ++t) {
        bf16x8 b0 = nb0, b1 = nb1;
        if (t < 15) {
            const short* src = kwb + (size_t)(t + 1) * 16 * HD_ + (size_t)lr * HD_ + lg * 8;
            nb0 = *reinterpret_cast<const bf16x8*>(src);
            nb1 = *reinterpret_cast<const bf16x8*>(src + 32);
        }
#pragma unroll
        for (int mt = 0; mt < 4; ++mt) {
            f32x4 acc = {0.f, 0.f, 0.f, 0.f};
            acc = __builtin_amdgcn_mfma_f32_16x16x32_bf16(a[mt][0], b0, acc, 0, 0, 0);
            acc = __builtin_amdgcn_mfma_f32_16x16x32_bf16(a[mt][1], b1, acc, 0, 0, 0);
#pragma unroll
            for (int r = 0; r < 4; ++r) rmax[mt][r] = fmaxf(rmax[mt][r], acc[r]);
        }
    }
    // reduce across the 16 cols held by lanes sharing lg
#pragma unroll
    for (int mt = 0; mt < 4; ++mt)
#pragma unroll
        for (int r = 0; r < 4; ++r) {
            float m = rmax[mt][r];
            m = fmaxf(m, __shfl_xor(m, 1));
            m = fmaxf(m, __shfl_xor(m, 2));
            m = fmaxf(m, __shfl_xor(m, 4));
            m = fmaxf(m, __shfl_xor(m, 8));
            rmax[mt][r] = m;
        }
    __shared__ float sm[4][64];
    if (lr == 0) {
#pragma unroll
        for (int mt = 0; mt < 4; ++mt)
#pragma unroll
            for (int r = 0; r < 4; ++r) sm[wave][mt * 16 + lg * 4 + r] = rmax[mt][r];
    }
    __syncthreads();
    if (threadIdx.x < 64) {
        float m = fmaxf(fmaxf(sm[0][threadIdx.x], sm[1][threadIdx.x]),
                        fmaxf(sm[2][threadIdx.x], sm[3][threadIdx.x]));
        am[(size_t)(b * NH_ + h) * N_ + n0 + threadIdx.x] = SCALE * m;
    }
}

// ---------------------------------------------------------------------------
// out[b,o,n] = pv[b,o] * (sum_h am[b,h,n]) + bproj[o]
__global__ void k_final(const float* __restrict__ pv, const float* __restrict__ am,
                        const float* __restrict__ bproj, float* __restrict__ out) {
    int b = blockIdx.y;
    int n = blockIdx.x * 256 + threadIdx.x;
    float s = 0.f;
#pragma unroll
    for (int h = 0; h < NH_; ++h) s += am[((size_t)b * NH_ + h) * N_ + n];
    const float* pvb = pv + b * C_;
    float* ob = out + (size_t)b * C_ * N_ + n;
    for (int o = 0; o < C_; ++o) ob[(size_t)o * N_] = pvb[o] * s + bproj[o];
}

// ---------------------------------------------------------------------------
extern "C" void kernel_launch(void* const* d_in, const int* in_sizes, int n_in,
                              void* d_out, int out_size, void* d_ws, size_t ws_size,
                              hipStream_t stream) {
    const float* x     = (const float*)d_in[0];
    // d_in[1] = y (unused by forward)
    const float* Wq    = (const float*)d_in[2];
    const float* Wk    = (const float*)d_in[3];
    const float* Wsr   = (const float*)d_in[4];
    const float* bsr   = (const float*)d_in[5];
    const float* gamma = (const float*)d_in[6];
    const float* beta  = (const float*)d_in[7];
    const float* mean  = (const float*)d_in[8];
    const float* var   = (const float*)d_in[9];
    const float* Wproj = (const float*)d_in[10];
    const float* bproj = (const float*)d_in[11];
    float* out = (float*)d_out;

    char* ws = (char*)d_ws;
    // workspace layout (~28.7 MB total)
    float*          v   = (float*)(ws);                         // 8 KB
    float*          pv  = (float*)(ws + 8192);                  // 8 KB
    __hip_bfloat16* q2  = (__hip_bfloat16*)(ws + 16384);        // 16 MB  [b,h,n,d] bf16
    __hip_bfloat16* k3  = (__hip_bfloat16*)(ws + 16384 + 16777216);           // 4 MB [b,h,p,d] bf16
    float*          xsr = (float*)(ws + 16384 + 16777216 + 4194304);          // 8 MB
    float*          am  = (float*)(ws + 16384 + 16777216 + 4194304 + 8388608);// 512 KB

    k_vmean<<<dim3(B_ * C_), 256, 0, stream>>>(x, v);
    k_pv<<<dim3(B_ * C_ / 4), 256, 0, stream>>>(Wproj, v, pv);
    k_qgemm<<<dim3(N_ / 64, C_ / 64, B_), 256, 0, stream>>>(Wq, x, q2);
    k_conv<<<dim3(NK / 64, C_ / 64, B_), 256, 0, stream>>>(Wsr, x, bsr, gamma, beta, mean, var, xsr);
    k_kgemm<<<dim3(NK / 64, C_ / 64, B_), 256, 0, stream>>>(Wk, xsr, k3);
    k_attn_mfma<<<dim3(N_ / 64, NH_, B_), 256, 0, stream>>>((const short*)q2, (const short*)k3, am);
    k_final<<<dim3(N_ / 256, B_), 256, 0, stream>>>(pv, am, bproj, out);
}

// Round 3
// 159.753 us; speedup vs baseline: 3.3978x; 2.3652x over previous
//
#include <hip/hip_runtime.h>
#include <hip/hip_bf16.h>

// Problem constants (fixed by reference setup_inputs)
constexpr int B_ = 4, C_ = 512, N_ = 4096, NH_ = 8, HD_ = 64;
constexpr int NK = 1024;            // (64/2)*(64/2)
constexpr float SCALE = 0.125f;     // HD^-0.5
constexpr float EPS = 1e-5f;

typedef __attribute__((ext_vector_type(8))) short bf16x8;
typedef __attribute__((ext_vector_type(4))) float f32x4;

__device__ __forceinline__ short bf16s(float f) {
    __hip_bfloat16 h = __float2bfloat16(f);
    return *reinterpret_cast<short*>(&h);
}

#define GLD16(gp, lp)                                                                     \
    __builtin_amdgcn_global_load_lds((const __attribute__((address_space(1))) void*)(gp), \
                                     (__attribute__((address_space(3))) void*)(lp), 16, 0, 0)

// ---------------------------------------------------------------------------
// x [b,c,n] fp32 -> xT [b,n,c] bf16, im2colT imp [b, p, kk=2048] bf16, v[b,c] mean (atomics)
// block: (y-row of 64x64 image, 64-c tile, b). LDS 64x64 transpose tile.
__global__ __launch_bounds__(256) void k_xprep(const float* __restrict__ x,
                                               short* __restrict__ xT,
                                               short* __restrict__ imp,
                                               float* __restrict__ v) {
    const int b = blockIdx.z, ct = blockIdx.y, y = blockIdx.x;  // y = n-tile = image row
    __shared__ float t[64][65];
    const int tid = threadIdx.x;
    {
        const int cc = tid >> 2, q = tid & 3;
        const float* xr = x + ((size_t)(b * C_ + ct * 64 + cc)) * N_ + y * 64;
        float s = 0.f;
#pragma unroll
        for (int jj = 0; jj < 4; ++jj) {
            float4 f = *reinterpret_cast<const float4*>(&xr[q * 16 + jj * 4]);
            int n = q * 16 + jj * 4;
            t[n + 0][cc] = f.x; t[n + 1][cc] = f.y;
            t[n + 2][cc] = f.z; t[n + 3][cc] = f.w;
            s += f.x + f.y + f.z + f.w;
        }
        s += __shfl_xor(s, 1);
        s += __shfl_xor(s, 2);
        if (q == 0) atomicAdd(&v[b * C_ + ct * 64 + cc], s * (1.f / N_));
    }
    __syncthreads();
    {   // xT [b][n][c] write
        const int n = tid >> 2, c0 = (tid & 3) * 16;
        bf16x8 u0, u1;
#pragma unroll
        for (int j = 0; j < 8; ++j) {
            u0[j] = bf16s(t[n][c0 + j]);
            u1[j] = bf16s(t[n][c0 + 8 + j]);
        }
        short* dst = xT + ((size_t)(b * N_ + y * 64 + n)) * C_ + ct * 64 + c0;
        *reinterpret_cast<bf16x8*>(dst) = u0;
        *reinterpret_cast<bf16x8*>(dst + 8) = u1;
    }
    {   // im2colT write: p = (y>>1)*32+ox, kk = ci*4 + (y&1)*2 + dx
        const int ci = tid & 63, oxg = tid >> 6;
        const int kkb = (ct * 64 + ci) * 4 + (y & 1) * 2;
        const int pb = (y >> 1) * 32;
#pragma unroll
        for (int jj = 0; jj < 8; ++jj) {
            int ox = oxg * 8 + jj;
            short2 pr;
            pr.x = bf16s(t[2 * ox][ci]);
            pr.y = bf16s(t[2 * ox + 1][ci]);
            *reinterpret_cast<short2*>(&imp[((size_t)(b * NK + pb + ox)) * 2048 + kkb]) = pr;
        }
    }
}

// ---------------------------------------------------------------------------
// Weight prep: Wq->bf16; Wk' = Wk*s (bf16); bk[o] = sum_c Wk[o,c]*(s*(bsr-mean)+beta)
__global__ __launch_bounds__(256) void k_wprep(const float* __restrict__ Wq, const float* __restrict__ Wk,
                                               const float* __restrict__ gamma, const float* __restrict__ beta,
                                               const float* __restrict__ mean, const float* __restrict__ var,
                                               const float* __restrict__ bsr,
                                               short* __restrict__ Wq16, short* __restrict__ Wkp16,
                                               float* __restrict__ bk) {
    const int o = blockIdx.x, tid = threadIdx.x;
    float acc = 0.f;
    for (int c = tid; c < C_; c += 256) {
        float sc = rsqrtf(var[c] + EPS) * gamma[c];
        float wk = Wk[o * C_ + c];
        Wkp16[o * C_ + c] = bf16s(wk * sc);
        Wq16[o * C_ + c] = bf16s(Wq[o * C_ + c]);
        acc += wk * (sc * (bsr[c] - mean[c]) + beta[c]);
    }
    for (int m = 32; m; m >>= 1) acc += __shfl_xor(acc, m);
    __shared__ float r4[4];
    if ((tid & 63) == 0) r4[tid >> 6] = acc;
    __syncthreads();
    if (tid == 0) bk[o] = r4[0] + r4[1] + r4[2] + r4[3];
}

// Wsr [co][2048] fp32 -> WsrT [kk][co] bf16 (64x64 LDS tile transpose)
__global__ __launch_bounds__(256) void k_wsrT(const float* __restrict__ Wsr, short* __restrict__ WsrT) {
    const int kt = blockIdx.x, ot = blockIdx.y;
    __shared__ float t[64][65];
    const int tid = threadIdx.x;
    {
        const int cc = tid >> 2, q = tid & 3;
        const float* xr = Wsr + (size_t)(ot * 64 + cc) * 2048 + kt * 64;
#pragma unroll
        for (int jj = 0; jj < 4; ++jj) {
            float4 f = *reinterpret_cast<const float4*>(&xr[q * 16 + jj * 4]);
            int n = q * 16 + jj * 4;
            t[n + 0][cc] = f.x; t[n + 1][cc] = f.y;
            t[n + 2][cc] = f.z; t[n + 3][cc] = f.w;
        }
    }
    __syncthreads();
    {
        const int n = tid >> 2, c0 = (tid & 3) * 16;
        bf16x8 u0, u1;
#pragma unroll
        for (int j = 0; j < 8; ++j) {
            u0[j] = bf16s(t[n][c0 + j]);
            u1[j] = bf16s(t[n][c0 + 8 + j]);
        }
        short* dst = WsrT + (size_t)(kt * 64 + n) * C_ + ot * 64 + c0;
        *reinterpret_cast<bf16x8*>(dst) = u0;
        *reinterpret_cast<bf16x8*>(dst + 8) = u1;
    }
}

// ---------------------------------------------------------------------------
// m97-style GEMM core: C[MT*32 x 128] += A[M rows][K] * B[N rows][K]^T
// 256 thr = 4 waves (2x2). BK=64, single-buffered LDS, global_load_lds width 16.
// MFMA conv.: C row (lg*4+r) = A-dim, C col (lr) = B-dim.
template <int MT>
__device__ __forceinline__ void gemm_core(const short* __restrict__ Ag,
                                          const short* __restrict__ Bg, int K,
                                          f32x4 (&acc)[MT][4]) {
    __shared__ short Abuf[MT * 32 * 64];
    __shared__ short Bbuf[128 * 64];
    const int tid = threadIdx.x;
    const int w = tid >> 6, l = tid & 63;
    const int lr = l & 15, lg = l >> 4;
    const int wm = w >> 1, wn = w & 1;
    const int srow = tid >> 3, scol = (tid & 7) * 8;
    char* AbufC = (char*)Abuf;
    char* BbufC = (char*)Bbuf;
    for (int kt = 0; kt < K; kt += 64) {
#pragma unroll
        for (int i = 0; i < MT; ++i)
            GLD16(Ag + (size_t)(i * 32 + srow) * K + kt + scol, AbufC + i * 4096 + w * 1024 + l * 16);
#pragma unroll
        for (int i = 0; i < 4; ++i)
            GLD16(Bg + (size_t)(i * 32 + srow) * K + kt + scol, BbufC + i * 4096 + w * 1024 + l * 16);
        __syncthreads();
        bf16x8 af[MT][2], bfv[4][2];
#pragma unroll
        for (int mt = 0; mt < MT; ++mt)
#pragma unroll
            for (int ks = 0; ks < 2; ++ks)
                af[mt][ks] = *reinterpret_cast<const bf16x8*>(
                    &Abuf[(wm * MT * 16 + mt * 16 + lr) * 64 + ks * 32 + lg * 8]);
#pragma unroll
        for (int nt = 0; nt < 4; ++nt)
#pragma unroll
            for (int ks = 0; ks < 2; ++ks)
                bfv[nt][ks] = *reinterpret_cast<const bf16x8*>(
                    &Bbuf[(wn * 64 + nt * 16 + lr) * 64 + ks * 32 + lg * 8]);
#pragma unroll
        for (int mt = 0; mt < MT; ++mt)
#pragma unroll
            for (int nt = 0; nt < 4; ++nt) {
                acc[mt][nt] = __builtin_amdgcn_mfma_f32_16x16x32_bf16(af[mt][0], bfv[nt][0], acc[mt][nt], 0, 0, 0);
                acc[mt][nt] = __builtin_amdgcn_mfma_f32_16x16x32_bf16(af[mt][1], bfv[nt][1], acc[mt][nt], 0, 0, 0);
            }
        __syncthreads();
    }
}

// Wck[o][kk] = sum_co Wk'[o,co] * WsrT[kk,co]   (M=512 BM=64, N=2048, K=512)
__global__ __launch_bounds__(256) void k_gemm_wck(const short* __restrict__ Wkp16,
                                                  const short* __restrict__ WsrT,
                                                  short* __restrict__ Wck16) {
    f32x4 acc[2][4];
#pragma unroll
    for (int i = 0; i < 2; ++i)
#pragma unroll
        for (int j = 0; j < 4; ++j) acc[i][j] = (f32x4){0.f, 0.f, 0.f, 0.f};
    const int m0 = blockIdx.y * 64, n0 = blockIdx.x * 128;
    gemm_core<2>(Wkp16 + (size_t)m0 * 512, WsrT + (size_t)n0 * 512, 512, acc);
    const int tid = threadIdx.x, l = tid & 63, w = tid >> 6;
    const int lr = l & 15, lg = l >> 4, wm = w >> 1, wn = w & 1;
#pragma unroll
    for (int mt = 0; mt < 2; ++mt)
#pragma unroll
        for (int nt = 0; nt < 4; ++nt) {
            int kk = n0 + wn * 64 + nt * 16 + lr;
#pragma unroll
            for (int r = 0; r < 4; ++r) {
                int o = m0 + wm * 32 + mt * 16 + lg * 4 + r;
                Wck16[(size_t)o * 2048 + kk] = bf16s(acc[mt][nt][r]);
            }
        }
}

// q2[b,h,n,d] = Wq @ x : A = xT rows (b*4096+n), B = Wq16 rows o. M=16384,N=512,K=512
__global__ __launch_bounds__(256) void k_gemm_q(const short* __restrict__ xT,
                                                const short* __restrict__ Wq16,
                                                short* __restrict__ q2) {
    f32x4 acc[4][4];
#pragma unroll
    for (int i = 0; i < 4; ++i)
#pragma unroll
        for (int j = 0; j < 4; ++j) acc[i][j] = (f32x4){0.f, 0.f, 0.f, 0.f};
    const int m0 = blockIdx.y * 128, n0 = blockIdx.x * 128;
    gemm_core<4>(xT + (size_t)m0 * 512, Wq16 + (size_t)n0 * 512, 512, acc);
    const int tid = threadIdx.x, l = tid & 63, w = tid >> 6;
    const int lr = l & 15, lg = l >> 4, wm = w >> 1, wn = w & 1;
#pragma unroll
    for (int mt = 0; mt < 4; ++mt)
#pragma unroll
        for (int nt = 0; nt < 4; ++nt) {
            int o = n0 + wn * 64 + nt * 16 + lr;
            int h = o >> 6, d = o & 63;
#pragma unroll
            for (int r = 0; r < 4; ++r) {
                int row = m0 + wm * 64 + mt * 16 + lg * 4 + r;
                int b = row >> 12, n = row & 4095;
                q2[(((size_t)(b * NH_ + h)) * N_ + n) * HD_ + d] = bf16s(acc[mt][nt][r]);
            }
        }
}

// k3[b,h,p,d] = Wck @ im2colT + bk : A = imp rows (b*1024+p), B = Wck16 rows o. M=4096,N=512,K=2048
__global__ __launch_bounds__(256) void k_gemm_k(const short* __restrict__ imp,
                                                const short* __restrict__ Wck16,
                                                const float* __restrict__ bk,
                                                short* __restrict__ k3) {
    f32x4 acc[4][4];
#pragma unroll
    for (int i = 0; i < 4; ++i)
#pragma unroll
        for (int j = 0; j < 4; ++j) acc[i][j] = (f32x4){0.f, 0.f, 0.f, 0.f};
    const int m0 = blockIdx.y * 128, n0 = blockIdx.x * 128;
    gemm_core<4>(imp + (size_t)m0 * 2048, Wck16 + (size_t)n0 * 2048, 2048, acc);
    const int tid = threadIdx.x, l = tid & 63, w = tid >> 6;
    const int lr = l & 15, lg = l >> 4, wm = w >> 1, wn = w & 1;
#pragma unroll
    for (int mt = 0; mt < 4; ++mt)
#pragma unroll
        for (int nt = 0; nt < 4; ++nt) {
            int o = n0 + wn * 64 + nt * 16 + lr;
            int h = o >> 6, d = o & 63;
            float bo = bk[o];
#pragma unroll
            for (int r = 0; r < 4; ++r) {
                int row = m0 + wm * 64 + mt * 16 + lg * 4 + r;
                int b = row >> 10, p = row & 1023;
                k3[(((size_t)(b * NH_ + h)) * NK + p) * HD_ + d] = bf16s(acc[mt][nt][r] + bo);
            }
        }
}

// ---------------------------------------------------------------------------
// attention: am[b,h,n] = SCALE * max_p sum_d q[n,d]*k[p,d]
// A = k3 (rows p), B = q2 (cols n). Block: 64 n, 4 waves split 1024 p (16 tiles of 16).
__global__ __launch_bounds__(256) void k_attn2(const short* __restrict__ k3,
                                               const short* __restrict__ q2,
                                               float* __restrict__ am) {
    const int b = blockIdx.z, h = blockIdx.y, n0 = blockIdx.x * 64;
    const int w = threadIdx.x >> 6, l = threadIdx.x & 63;
    const int lr = l & 15, lg = l >> 4;
    const short* qb = q2 + ((size_t)(b * NH_ + h)) * N_ * HD_;
    const short* kb = k3 + ((size_t)(b * NH_ + h)) * NK * HD_;

    bf16x8 bq[4][2];
#pragma unroll
    for (int nt = 0; nt < 4; ++nt)
#pragma unroll
        for (int ks = 0; ks < 2; ++ks)
            bq[nt][ks] = *reinterpret_cast<const bf16x8*>(
                &qb[(size_t)(n0 + nt * 16 + lr) * HD_ + ks * 32 + lg * 8]);

    float rmax[4];
#pragma unroll
    for (int nt = 0; nt < 4; ++nt) rmax[nt] = -3.4e38f;

    const short* kw = kb + (size_t)(w * 256) * HD_;
    const short* s0 = kw + (size_t)lr * HD_ + lg * 8;
    bf16x8 a0 = *reinterpret_cast<const bf16x8*>(s0);
    bf16x8 a1 = *reinterpret_cast<const bf16x8*>(s0 + 32);
    for (int t = 0; t < 16; ++t) {
        bf16x8 c0 = a0, c1 = a1;
        if (t < 15) {
            const short* s2 = kw + (size_t)((t + 1) * 16 + lr) * HD_ + lg * 8;
            a0 = *reinterpret_cast<const bf16x8*>(s2);
            a1 = *reinterpret_cast<const bf16x8*>(s2 + 32);
        }
#pragma unroll
        for (int nt = 0; nt < 4; ++nt) {
            f32x4 acc = {0.f, 0.f, 0.f, 0.f};
            acc = __builtin_amdgcn_mfma_f32_16x16x32_bf16(c0, bq[nt][0], acc, 0, 0, 0);
            acc = __builtin_amdgcn_mfma_f32_16x16x32_bf16(c1, bq[nt][1], acc, 0, 0, 0);
            float m = fmaxf(fmaxf(acc[0], acc[1]), fmaxf(acc[2], acc[3]));
            rmax[nt] = fmaxf(rmax[nt], m);
        }
    }
#pragma unroll
    for (int nt = 0; nt < 4; ++nt) {
        float m = rmax[nt];
        m = fmaxf(m, __shfl_xor(m, 16));
        m = fmaxf(m, __shfl_xor(m, 32));
        rmax[nt] = m;
    }
    __shared__ float sm[4][64];
    if (lg == 0) {
#pragma unroll
        for (int nt = 0; nt < 4; ++nt) sm[w][nt * 16 + lr] = rmax[nt];
    }
    __syncthreads();
    if (threadIdx.x < 64) {
        float m = fmaxf(fmaxf(sm[0][threadIdx.x], sm[1][threadIdx.x]),
                        fmaxf(sm[2][threadIdx.x], sm[3][threadIdx.x]));
        am[((size_t)(b * NH_ + h)) * N_ + n0 + threadIdx.x] = SCALE * m;
    }
}

// ---------------------------------------------------------------------------
// pv[b,o] = sum_c Wproj[o,c] * v[b,c]
__global__ void k_pv(const float* __restrict__ Wproj, const float* __restrict__ v,
                     float* __restrict__ pv) {
    int idx = blockIdx.x * 4 + (threadIdx.x >> 6);
    int lane = threadIdx.x & 63;
    int b = idx / C_, o = idx % C_;
    float s = 0.f;
    for (int c = lane; c < C_; c += 64) s += Wproj[o * C_ + c] * v[b * C_ + c];
    for (int m = 32; m; m >>= 1) s += __shfl_xor(s, m);
    if (lane == 0) pv[idx] = s;
}

// out[b,o,n] = pv[b,o] * (sum_h am[b,h,n]) + bproj[o]
__global__ void k_final(const float* __restrict__ pv, const float* __restrict__ am,
                        const float* __restrict__ bproj, float* __restrict__ out) {
    const int b = blockIdx.z, o0 = blockIdx.y * 64;
    const int n = blockIdx.x * 1024 + threadIdx.x * 4;
    float4 s = {0.f, 0.f, 0.f, 0.f};
#pragma unroll
    for (int h = 0; h < NH_; ++h) {
        float4 a = *reinterpret_cast<const float4*>(&am[((size_t)(b * NH_ + h)) * N_ + n]);
        s.x += a.x; s.y += a.y; s.z += a.z; s.w += a.w;
    }
    float* ob = out + (size_t)b * C_ * N_ + n;
    const float* pvb = pv + b * C_;
#pragma unroll 4
    for (int o = o0; o < o0 + 64; ++o) {
        float p = pvb[o], bp = bproj[o];
        float4 r = {p * s.x + bp, p * s.y + bp, p * s.z + bp, p * s.w + bp};
        *reinterpret_cast<float4*>(&ob[(size_t)o * N_]) = r;
    }
}

// ---------------------------------------------------------------------------
extern "C" void kernel_launch(void* const* d_in, const int* in_sizes, int n_in,
                              void* d_out, int out_size, void* d_ws, size_t ws_size,
                              hipStream_t stream) {
    const float* x     = (const float*)d_in[0];
    const float* Wq    = (const float*)d_in[2];
    const float* Wk    = (const float*)d_in[3];
    const float* Wsr   = (const float*)d_in[4];
    const float* bsr   = (const float*)d_in[5];
    const float* gamma = (const float*)d_in[6];
    const float* beta  = (const float*)d_in[7];
    const float* mean  = (const float*)d_in[8];
    const float* var   = (const float*)d_in[9];
    const float* Wproj = (const float*)d_in[10];
    const float* bproj = (const float*)d_in[11];
    float* out = (float*)d_out;

    char* ws = (char*)d_ws;
    // workspace layout (43.5 MB): q2 aliases imp (imp dead after k_gemm_k)
    float* v     = (float*)(ws + 0);         // 8 KB
    float* pv    = (float*)(ws + 8192);      // 8 KB
    float* bk    = (float*)(ws + 16384);     // 4 KB
    float* am    = (float*)(ws + 20480);     // 512 KB
    short* Wq16  = (short*)(ws + 544768);    // 512 KB
    short* Wkp16 = (short*)(ws + 1069056);   // 512 KB
    short* WsrT  = (short*)(ws + 1593344);   // 2 MB
    short* Wck16 = (short*)(ws + 3690496);   // 2 MB
    short* xT    = (short*)(ws + 5787648);   // 16 MB [b,n,c]
    short* imp   = (short*)(ws + 22564864);  // 16 MB [b,p,kk] ; reused as q2 [b,h,n,d]
    short* k3    = (short*)(ws + 39342080);  // 4 MB  [b,h,p,d]
    short* q2    = imp;

    hipMemsetAsync(v, 0, B_ * C_ * sizeof(float), stream);
    k_xprep<<<dim3(64, 8, B_), 256, 0, stream>>>(x, xT, imp, v);
    k_wprep<<<dim3(512), 256, 0, stream>>>(Wq, Wk, gamma, beta, mean, var, bsr, Wq16, Wkp16, bk);
    k_wsrT<<<dim3(32, 8), 256, 0, stream>>>(Wsr, WsrT);
    k_gemm_wck<<<dim3(16, 8), 256, 0, stream>>>(Wkp16, WsrT, Wck16);
    k_gemm_k<<<dim3(4, 32), 256, 0, stream>>>(imp, Wck16, bk, k3);     // imp consumed here
    k_gemm_q<<<dim3(4, 128), 256, 0, stream>>>(xT, Wq16, q2);          // q2 overwrites imp
    k_attn2<<<dim3(64, NH_, B_), 256, 0, stream>>>(k3, q2, am);
    k_pv<<<dim3(B_ * C_ / 4), 256, 0, stream>>>(Wproj, v, pv);
    k_final<<<dim3(4, 8, B_), 256, 0, stream>>>(pv, am, bproj, out);
}

// Round 4
// 134.458 us; speedup vs baseline: 4.0370x; 1.1881x over previous
//
#include <hip/hip_runtime.h>
#include <hip/hip_bf16.h>

// Problem constants (fixed by reference setup_inputs)
constexpr int B_ = 4, C_ = 512, N_ = 4096, NH_ = 8, HD_ = 64;
constexpr int NK = 1024;            // (64/2)*(64/2)
constexpr float SCALE = 0.125f;     // HD^-0.5
constexpr float EPS = 1e-5f;

typedef __attribute__((ext_vector_type(8))) short bf16x8;
typedef __attribute__((ext_vector_type(4))) float f32x4;

__device__ __forceinline__ short bf16s(float f) {
    __hip_bfloat16 h = __float2bfloat16(f);
    return *reinterpret_cast<short*>(&h);
}

#define GLD16(gp, lp)                                                                     \
    __builtin_amdgcn_global_load_lds((const __attribute__((address_space(1))) void*)(gp), \
                                     (__attribute__((address_space(3))) void*)(lp), 16, 0, 0)

// ---------------------------------------------------------------------------
// x [b,c,n] fp32 -> xT [b,n,c] bf16, im2colT imp [b, p, kk=2048] bf16, v[b,c] mean (atomics)
__global__ __launch_bounds__(256) void k_xprep(const float* __restrict__ x,
                                               short* __restrict__ xT,
                                               short* __restrict__ imp,
                                               float* __restrict__ v) {
    const int b = blockIdx.z, ct = blockIdx.y, y = blockIdx.x;  // y = image row
    __shared__ float t[64][65];
    const int tid = threadIdx.x;
    {
        const int cc = tid >> 2, q = tid & 3;
        const float* xr = x + ((size_t)(b * C_ + ct * 64 + cc)) * N_ + y * 64;
        float s = 0.f;
#pragma unroll
        for (int jj = 0; jj < 4; ++jj) {
            float4 f = *reinterpret_cast<const float4*>(&xr[q * 16 + jj * 4]);
            int n = q * 16 + jj * 4;
            t[n + 0][cc] = f.x; t[n + 1][cc] = f.y;
            t[n + 2][cc] = f.z; t[n + 3][cc] = f.w;
            s += f.x + f.y + f.z + f.w;
        }
        s += __shfl_xor(s, 1);
        s += __shfl_xor(s, 2);
        if (q == 0) atomicAdd(&v[b * C_ + ct * 64 + cc], s * (1.f / N_));
    }
    __syncthreads();
    {   // xT [b][n][c] write
        const int n = tid >> 2, c0 = (tid & 3) * 16;
        bf16x8 u0, u1;
#pragma unroll
        for (int j = 0; j < 8; ++j) {
            u0[j] = bf16s(t[n][c0 + j]);
            u1[j] = bf16s(t[n][c0 + 8 + j]);
        }
        short* dst = xT + ((size_t)(b * N_ + y * 64 + n)) * C_ + ct * 64 + c0;
        *reinterpret_cast<bf16x8*>(dst) = u0;
        *reinterpret_cast<bf16x8*>(dst + 8) = u1;
    }
    {   // im2colT write: p = (y>>1)*32+ox, kk = ci*4 + (y&1)*2 + dx
        const int ci = tid & 63, oxg = tid >> 6;
        const int kkb = (ct * 64 + ci) * 4 + (y & 1) * 2;
        const int pb = (y >> 1) * 32;
#pragma unroll
        for (int jj = 0; jj < 8; ++jj) {
            int ox = oxg * 8 + jj;
            short2 pr;
            pr.x = bf16s(t[2 * ox][ci]);
            pr.y = bf16s(t[2 * ox + 1][ci]);
            *reinterpret_cast<short2*>(&imp[((size_t)(b * NK + pb + ox)) * 2048 + kkb]) = pr;
        }
    }
}

// ---------------------------------------------------------------------------
// Weight prep: Wq->bf16; Wk' = Wk*s (bf16); bk[o] = sum_c Wk[o,c]*(s*(bsr-mean)+beta)
__global__ __launch_bounds__(256) void k_wprep(const float* __restrict__ Wq, const float* __restrict__ Wk,
                                               const float* __restrict__ gamma, const float* __restrict__ beta,
                                               const float* __restrict__ mean, const float* __restrict__ var,
                                               const float* __restrict__ bsr,
                                               short* __restrict__ Wq16, short* __restrict__ Wkp16,
                                               float* __restrict__ bk) {
    const int o = blockIdx.x, tid = threadIdx.x;
    float acc = 0.f;
    for (int c = tid; c < C_; c += 256) {
        float sc = rsqrtf(var[c] + EPS) * gamma[c];
        float wk = Wk[o * C_ + c];
        Wkp16[o * C_ + c] = bf16s(wk * sc);
        Wq16[o * C_ + c] = bf16s(Wq[o * C_ + c]);
        acc += wk * (sc * (bsr[c] - mean[c]) + beta[c]);
    }
    for (int m = 32; m; m >>= 1) acc += __shfl_xor(acc, m);
    __shared__ float r4[4];
    if ((tid & 63) == 0) r4[tid >> 6] = acc;
    __syncthreads();
    if (tid == 0) bk[o] = r4[0] + r4[1] + r4[2] + r4[3];
}

// Wsr [co][2048] fp32 -> WsrT [kk][co] bf16 (64x64 LDS tile transpose)
__global__ __launch_bounds__(256) void k_wsrT(const float* __restrict__ Wsr, short* __restrict__ WsrT) {
    const int kt = blockIdx.x, ot = blockIdx.y;
    __shared__ float t[64][65];
    const int tid = threadIdx.x;
    {
        const int cc = tid >> 2, q = tid & 3;
        const float* xr = Wsr + (size_t)(ot * 64 + cc) * 2048 + kt * 64;
#pragma unroll
        for (int jj = 0; jj < 4; ++jj) {
            float4 f = *reinterpret_cast<const float4*>(&xr[q * 16 + jj * 4]);
            int n = q * 16 + jj * 4;
            t[n + 0][cc] = f.x; t[n + 1][cc] = f.y;
            t[n + 2][cc] = f.z; t[n + 3][cc] = f.w;
        }
    }
    __syncthreads();
    {
        const int n = tid >> 2, c0 = (tid & 3) * 16;
        bf16x8 u0, u1;
#pragma unroll
        for (int j = 0; j < 8; ++j) {
            u0[j] = bf16s(t[n][c0 + j]);
            u1[j] = bf16s(t[n][c0 + 8 + j]);
        }
        short* dst = WsrT + (size_t)(kt * 64 + n) * C_ + ot * 64 + c0;
        *reinterpret_cast<bf16x8*>(dst) = u0;
        *reinterpret_cast<bf16x8*>(dst + 8) = u1;
    }
}

// ---------------------------------------------------------------------------
// m97-style GEMM core: acc += A[128 rows][K] * B[128 rows][K]^T (both K-contig)
// 256 thr = 4 waves (2x2). BK=64, single-buffered LDS, global_load_lds width 16.
// C row (lg*4+r) = A-dim, C col (lr) = B-dim.
template <int MT>
__device__ __forceinline__ void gemm_core(const short* __restrict__ Ag,
                                          const short* __restrict__ Bg, int K,
                                          short* Abuf, short* Bbuf,
                                          f32x4 (&acc)[MT][4]) {
    const int tid = threadIdx.x;
    const int w = tid >> 6, l = tid & 63;
    const int lr = l & 15, lg = l >> 4;
    const int wm = w >> 1, wn = w & 1;
    const int srow = tid >> 3, scol = (tid & 7) * 8;
    char* AbufC = (char*)Abuf;
    char* BbufC = (char*)Bbuf;
    for (int kt = 0; kt < K; kt += 64) {
#pragma unroll
        for (int i = 0; i < MT; ++i)
            GLD16(Ag + (size_t)(i * 32 + srow) * K + kt + scol, AbufC + i * 4096 + w * 1024 + l * 16);
#pragma unroll
        for (int i = 0; i < 4; ++i)
            GLD16(Bg + (size_t)(i * 32 + srow) * K + kt + scol, BbufC + i * 4096 + w * 1024 + l * 16);
        __syncthreads();
        bf16x8 af[MT][2], bfv[4][2];
#pragma unroll
        for (int mt = 0; mt < MT; ++mt)
#pragma unroll
            for (int ks = 0; ks < 2; ++ks)
                af[mt][ks] = *reinterpret_cast<const bf16x8*>(
                    &Abuf[(wm * MT * 16 + mt * 16 + lr) * 64 + ks * 32 + lg * 8]);
#pragma unroll
        for (int nt = 0; nt < 4; ++nt)
#pragma unroll
            for (int ks = 0; ks < 2; ++ks)
                bfv[nt][ks] = *reinterpret_cast<const bf16x8*>(
                    &Bbuf[(wn * 64 + nt * 16 + lr) * 64 + ks * 32 + lg * 8]);
#pragma unroll
        for (int mt = 0; mt < MT; ++mt)
#pragma unroll
            for (int nt = 0; nt < 4; ++nt) {
                acc[mt][nt] = __builtin_amdgcn_mfma_f32_16x16x32_bf16(af[mt][0], bfv[nt][0], acc[mt][nt], 0, 0, 0);
                acc[mt][nt] = __builtin_amdgcn_mfma_f32_16x16x32_bf16(af[mt][1], bfv[nt][1], acc[mt][nt], 0, 0, 0);
            }
        __syncthreads();
    }
}

// Wck[o][kk] = sum_co Wk'[o,co] * WsrT[kk,co]   (M=512 BM=64, N=2048, K=512)
__global__ __launch_bounds__(256) void k_gemm_wck(const short* __restrict__ Wkp16,
                                                  const short* __restrict__ WsrT,
                                                  short* __restrict__ Wck16) {
    __shared__ short Abuf[2 * 32 * 64];
    __shared__ short Bbuf[128 * 64];
    f32x4 acc[2][4];
#pragma unroll
    for (int i = 0; i < 2; ++i)
#pragma unroll
        for (int j = 0; j < 4; ++j) acc[i][j] = (f32x4){0.f, 0.f, 0.f, 0.f};
    const int m0 = blockIdx.y * 64, n0 = blockIdx.x * 128;
    gemm_core<2>(Wkp16 + (size_t)m0 * 512, WsrT + (size_t)n0 * 512, 512, Abuf, Bbuf, acc);
    const int tid = threadIdx.x, l = tid & 63, w = tid >> 6;
    const int lr = l & 15, lg = l >> 4, wm = w >> 1, wn = w & 1;
#pragma unroll
    for (int mt = 0; mt < 2; ++mt)
#pragma unroll
        for (int nt = 0; nt < 4; ++nt) {
            int kk = n0 + wn * 64 + nt * 16 + lr;
#pragma unroll
            for (int r = 0; r < 4; ++r) {
                int o = m0 + wm * 32 + mt * 16 + lg * 4 + r;
                Wck16[(size_t)o * 2048 + kk] = bf16s(acc[mt][nt][r]);
            }
        }
}

// ---------------------------------------------------------------------------
// Fused q-GEMM + k-GEMM. A = weights (rows o, M=512), B = activations.
//   blocks [0,128):   k3 = Wck16 @ imp^T + bk   (K=2048, N-dim = b*p = 4096)
//   blocks [128,640): q2 = Wq16  @ xT^T         (K=512,  N-dim = b*n = 16384)
// Heavy k-blocks first for load balance. bid_base supports split launches.
__global__ __launch_bounds__(256) void k_gemm_qk(const short* __restrict__ xT,
                                                 const short* __restrict__ Wq16,
                                                 const short* __restrict__ imp,
                                                 const short* __restrict__ Wck16,
                                                 const float* __restrict__ bk,
                                                 short* __restrict__ q2,
                                                 short* __restrict__ k3,
                                                 int bid_base) {
    __shared__ short Abuf[128 * 64];
    __shared__ short Bbuf[128 * 64];
    f32x4 acc[4][4];
#pragma unroll
    for (int i = 0; i < 4; ++i)
#pragma unroll
        for (int j = 0; j < 4; ++j) acc[i][j] = (f32x4){0.f, 0.f, 0.f, 0.f};
    const int bid = blockIdx.x + bid_base;
    const int tid = threadIdx.x, l = tid & 63, w = tid >> 6;
    const int lr = l & 15, lg = l >> 4, wm = w >> 1, wn = w & 1;
    if (bid < 128) {
        const int m0 = (bid & 3) * 128, n0 = (bid >> 2) * 128;
        gemm_core<4>(Wck16 + (size_t)m0 * 2048, imp + (size_t)n0 * 2048, 2048, Abuf, Bbuf, acc);
#pragma unroll
        for (int mt = 0; mt < 4; ++mt) {
            const int o0 = m0 + wm * 64 + mt * 16 + lg * 4;
            const int h = o0 >> 6, d0 = o0 & 63;
            const float4 bo = *reinterpret_cast<const float4*>(&bk[o0]);
#pragma unroll
            for (int nt = 0; nt < 4; ++nt) {
                int pg = n0 + wn * 64 + nt * 16 + lr;
                int b = pg >> 10, p = pg & 1023;
                short4 u;
                u.x = bf16s(acc[mt][nt][0] + bo.x);
                u.y = bf16s(acc[mt][nt][1] + bo.y);
                u.z = bf16s(acc[mt][nt][2] + bo.z);
                u.w = bf16s(acc[mt][nt][3] + bo.w);
                *reinterpret_cast<short4*>(&k3[(((size_t)(b * NH_ + h)) * NK + p) * HD_ + d0]) = u;
            }
        }
    } else {
        const int bq = bid - 128;
        const int m0 = (bq & 3) * 128, n0 = (bq >> 2) * 128;
        gemm_core<4>(Wq16 + (size_t)m0 * 512, xT + (size_t)n0 * 512, 512, Abuf, Bbuf, acc);
#pragma unroll
        for (int mt = 0; mt < 4; ++mt) {
            const int o0 = m0 + wm * 64 + mt * 16 + lg * 4;
            const int h = o0 >> 6, d0 = o0 & 63;
#pragma unroll
            for (int nt = 0; nt < 4; ++nt) {
                int ng = n0 + wn * 64 + nt * 16 + lr;
                int b = ng >> 12, n = ng & 4095;
                short4 u;
                u.x = bf16s(acc[mt][nt][0]);
                u.y = bf16s(acc[mt][nt][1]);
                u.z = bf16s(acc[mt][nt][2]);
                u.w = bf16s(acc[mt][nt][3]);
                *reinterpret_cast<short4*>(&q2[(((size_t)(b * NH_ + h)) * N_ + n) * HD_ + d0]) = u;
            }
        }
    }
}

// ---------------------------------------------------------------------------
// attention: am[b,h,n] = SCALE * max_p sum_d q[n,d]*k[p,d]
// A = k3 (rows p), B = q2 (cols n). Block: 128 n, 4 waves split 1024 p (16 tiles of 16).
__global__ __launch_bounds__(256) void k_attn2(const short* __restrict__ k3,
                                               const short* __restrict__ q2,
                                               float* __restrict__ am) {
    const int b = blockIdx.z, h = blockIdx.y, n0 = blockIdx.x * 128;
    const int w = threadIdx.x >> 6, l = threadIdx.x & 63;
    const int lr = l & 15, lg = l >> 4;
    const short* qb = q2 + ((size_t)(b * NH_ + h)) * N_ * HD_;
    const short* kb = k3 + ((size_t)(b * NH_ + h)) * NK * HD_;

    bf16x8 bq[8][2];
#pragma unroll
    for (int nt = 0; nt < 8; ++nt)
#pragma unroll
        for (int ks = 0; ks < 2; ++ks)
            bq[nt][ks] = *reinterpret_cast<const bf16x8*>(
                &qb[(size_t)(n0 + nt * 16 + lr) * HD_ + ks * 32 + lg * 8]);

    float rmax[8];
#pragma unroll
    for (int nt = 0; nt < 8; ++nt) rmax[nt] = -3.4e38f;

    const short* kw = kb + (size_t)(w * 256) * HD_;
    const short* s0 = kw + (size_t)lr * HD_ + lg * 8;
    bf16x8 a0 = *reinterpret_cast<const bf16x8*>(s0);
    bf16x8 a1 = *reinterpret_cast<const bf16x8*>(s0 + 32);
    for (int t = 0; t < 16; ++t) {
        bf16x8 c0 = a0, c1 = a1;
        if (t < 15) {
            const short* s2 = kw + (size_t)((t + 1) * 16 + lr) * HD_ + lg * 8;
            a0 = *reinterpret_cast<const bf16x8*>(s2);
            a1 = *reinterpret_cast<const bf16x8*>(s2 + 32);
        }
#pragma unroll
        for (int nt = 0; nt < 8; ++nt) {
            f32x4 acc = {0.f, 0.f, 0.f, 0.f};
            acc = __builtin_amdgcn_mfma_f32_16x16x32_bf16(c0, bq[nt][0], acc, 0, 0, 0);
            acc = __builtin_amdgcn_mfma_f32_16x16x32_bf16(c1, bq[nt][1], acc, 0, 0, 0);
            float m = fmaxf(fmaxf(acc[0], acc[1]), fmaxf(acc[2], acc[3]));
            rmax[nt] = fmaxf(rmax[nt], m);
        }
    }
#pragma unroll
    for (int nt = 0; nt < 8; ++nt) {
        float m = rmax[nt];
        m = fmaxf(m, __shfl_xor(m, 16));
        m = fmaxf(m, __shfl_xor(m, 32));
        rmax[nt] = m;
    }
    __shared__ float sm[4][128];
    if (lg == 0) {
#pragma unroll
        for (int nt = 0; nt < 8; ++nt) sm[w][nt * 16 + lr] = rmax[nt];
    }
    __syncthreads();
    if (threadIdx.x < 128) {
        float m = fmaxf(fmaxf(sm[0][threadIdx.x], sm[1][threadIdx.x]),
                        fmaxf(sm[2][threadIdx.x], sm[3][threadIdx.x]));
        am[((size_t)(b * NH_ + h)) * N_ + n0 + threadIdx.x] = SCALE * m;
    }
}

// ---------------------------------------------------------------------------
// pv[b,o] = sum_c Wproj[o,c] * v[b,c]
__global__ void k_pv(const float* __restrict__ Wproj, const float* __restrict__ v,
                     float* __restrict__ pv) {
    int idx = blockIdx.x * 4 + (threadIdx.x >> 6);
    int lane = threadIdx.x & 63;
    int b = idx / C_, o = idx % C_;
    float s = 0.f;
    for (int c = lane; c < C_; c += 64) s += Wproj[o * C_ + c] * v[b * C_ + c];
    for (int m = 32; m; m >>= 1) s += __shfl_xor(s, m);
    if (lane == 0) pv[idx] = s;
}

// out[b,o,n] = pv[b,o] * (sum_h am[b,h,n]) + bproj[o]
__global__ void k_final(const float* __restrict__ pv, const float* __restrict__ am,
                        const float* __restrict__ bproj, float* __restrict__ out) {
    const int b = blockIdx.z, o0 = blockIdx.y * 64;
    const int n = blockIdx.x * 1024 + threadIdx.x * 4;
    float4 s = {0.f, 0.f, 0.f, 0.f};
#pragma unroll
    for (int h = 0; h < NH_; ++h) {
        float4 a = *reinterpret_cast<const float4*>(&am[((size_t)(b * NH_ + h)) * N_ + n]);
        s.x += a.x; s.y += a.y; s.z += a.z; s.w += a.w;
    }
    float* ob = out + (size_t)b * C_ * N_ + n;
    const float* pvb = pv + b * C_;
#pragma unroll 4
    for (int o = o0; o < o0 + 64; ++o) {
        float p = pvb[o], bp = bproj[o];
        float4 r = {p * s.x + bp, p * s.y + bp, p * s.z + bp, p * s.w + bp};
        *reinterpret_cast<float4*>(&ob[(size_t)o * N_]) = r;
    }
}

// ---------------------------------------------------------------------------
extern "C" void kernel_launch(void* const* d_in, const int* in_sizes, int n_in,
                              void* d_out, int out_size, void* d_ws, size_t ws_size,
                              hipStream_t stream) {
    const float* x     = (const float*)d_in[0];
    const float* Wq    = (const float*)d_in[2];
    const float* Wk    = (const float*)d_in[3];
    const float* Wsr   = (const float*)d_in[4];
    const float* bsr   = (const float*)d_in[5];
    const float* gamma = (const float*)d_in[6];
    const float* beta  = (const float*)d_in[7];
    const float* mean  = (const float*)d_in[8];
    const float* var   = (const float*)d_in[9];
    const float* Wproj = (const float*)d_in[10];
    const float* bproj = (const float*)d_in[11];
    float* out = (float*)d_out;

    char* ws = (char*)d_ws;
    float* v     = (float*)(ws + 0);         // 8 KB
    float* pv    = (float*)(ws + 8192);      // 8 KB
    float* bk    = (float*)(ws + 16384);     // 4 KB
    float* am    = (float*)(ws + 20480);     // 512 KB
    short* Wq16  = (short*)(ws + 544768);    // 512 KB
    short* Wkp16 = (short*)(ws + 1069056);   // 512 KB
    short* WsrT  = (short*)(ws + 1593344);   // 2 MB
    short* Wck16 = (short*)(ws + 3690496);   // 2 MB
    short* xT    = (short*)(ws + 5787648);   // 16 MB [b,n,c]
    short* imp   = (short*)(ws + 22564864);  // 16 MB [b,p,kk]
    short* k3    = (short*)(ws + 39342080);  // 4 MB  [b,h,p,d]
    const size_t NEED_FUSED = 43536384 + 16777216;  // + separate q2
    short* q2 = (ws_size >= NEED_FUSED) ? (short*)(ws + 43536384) : imp;

    hipMemsetAsync(v, 0, B_ * C_ * sizeof(float), stream);
    k_xprep<<<dim3(64, 8, B_), 256, 0, stream>>>(x, xT, imp, v);
    k_wprep<<<dim3(512), 256, 0, stream>>>(Wq, Wk, gamma, beta, mean, var, bsr, Wq16, Wkp16, bk);
    k_wsrT<<<dim3(32, 8), 256, 0, stream>>>(Wsr, WsrT);
    k_gemm_wck<<<dim3(16, 8), 256, 0, stream>>>(Wkp16, WsrT, Wck16);
    if (ws_size >= NEED_FUSED) {
        k_gemm_qk<<<dim3(640), 256, 0, stream>>>(xT, Wq16, imp, Wck16, bk, q2, k3, 0);
    } else {  // q2 aliases imp: keep k-GEMM (reads imp) strictly before q-GEMM
        k_gemm_qk<<<dim3(128), 256, 0, stream>>>(xT, Wq16, imp, Wck16, bk, q2, k3, 0);
        k_gemm_qk<<<dim3(512), 256, 0, stream>>>(xT, Wq16, imp, Wck16, bk, q2, k3, 128);
    }
    k_attn2<<<dim3(32, NH_, B_), 256, 0, stream>>>(k3, q2, am);
    k_pv<<<dim3(B_ * C_ / 4), 256, 0, stream>>>(Wproj, v, pv);
    k_final<<<dim3(4, 8, B_), 256, 0, stream>>>(pv, am, bproj, out);
}

// Round 5
// 118.822 us; speedup vs baseline: 4.5682x; 1.1316x over previous
//
#include <hip/hip_runtime.h>
#include <hip/hip_bf16.h>

// Problem constants (fixed by reference setup_inputs)
constexpr int B_ = 4, C_ = 512, N_ = 4096, NH_ = 8, HD_ = 64;
constexpr int NK = 1024;            // (64/2)*(64/2)
constexpr float SCALE = 0.125f;     // HD^-0.5
constexpr float EPS = 1e-5f;

typedef __attribute__((ext_vector_type(8))) short bf16x8;
typedef __attribute__((ext_vector_type(4))) float f32x4;

__device__ __forceinline__ short bf16s(float f) {
    __hip_bfloat16 h = __float2bfloat16(f);
    return *reinterpret_cast<short*>(&h);
}

#define GLD16(gp, lp)                                                                     \
    __builtin_amdgcn_global_load_lds((const __attribute__((address_space(1))) void*)(gp), \
                                     (__attribute__((address_space(3))) void*)(lp), 16, 0, 0)

// ---------------------------------------------------------------------------
// x [b,c,n] fp32 -> xT [b,n,c] bf16 ; v[b,c] = mean_n x (atomics)
__global__ __launch_bounds__(256) void k_xprep(const float* __restrict__ x,
                                               short* __restrict__ xT,
                                               float* __restrict__ v) {
    const int b = blockIdx.z, ct = blockIdx.y, y = blockIdx.x;  // y = image row = n-tile
    __shared__ float t[64][65];
    const int tid = threadIdx.x;
    {
        const int cc = tid >> 2, q = tid & 3;
        const float* xr = x + ((size_t)(b * C_ + ct * 64 + cc)) * N_ + y * 64;
        float s = 0.f;
#pragma unroll
        for (int jj = 0; jj < 4; ++jj) {
            float4 f = *reinterpret_cast<const float4*>(&xr[q * 16 + jj * 4]);
            int n = q * 16 + jj * 4;
            t[n + 0][cc] = f.x; t[n + 1][cc] = f.y;
            t[n + 2][cc] = f.z; t[n + 3][cc] = f.w;
            s += f.x + f.y + f.z + f.w;
        }
        s += __shfl_xor(s, 1);
        s += __shfl_xor(s, 2);
        if (q == 0) atomicAdd(&v[b * C_ + ct * 64 + cc], s * (1.f / N_));
    }
    __syncthreads();
    {   // xT [b][n][c] write (coalesced 128B per row)
        const int n = tid >> 2, c0 = (tid & 3) * 16;
        bf16x8 u0, u1;
#pragma unroll
        for (int j = 0; j < 8; ++j) {
            u0[j] = bf16s(t[n][c0 + j]);
            u1[j] = bf16s(t[n][c0 + 8 + j]);
        }
        short* dst = xT + ((size_t)(b * N_ + y * 64 + n)) * C_ + ct * 64 + c0;
        *reinterpret_cast<bf16x8*>(dst) = u0;
        *reinterpret_cast<bf16x8*>(dst + 8) = u1;
    }
}

// ---------------------------------------------------------------------------
// Weight prep: Wq->bf16; Wk' = Wk*s (bf16); bk[o] = sum_c Wk[o,c]*(s*(bsr-mean)+beta)
__global__ __launch_bounds__(256) void k_wprep(const float* __restrict__ Wq, const float* __restrict__ Wk,
                                               const float* __restrict__ gamma, const float* __restrict__ beta,
                                               const float* __restrict__ mean, const float* __restrict__ var,
                                               const float* __restrict__ bsr,
                                               short* __restrict__ Wq16, short* __restrict__ Wkp16,
                                               float* __restrict__ bk) {
    const int o = blockIdx.x, tid = threadIdx.x;
    float acc = 0.f;
    for (int c = tid; c < C_; c += 256) {
        float sc = rsqrtf(var[c] + EPS) * gamma[c];
        float wk = Wk[o * C_ + c];
        Wkp16[o * C_ + c] = bf16s(wk * sc);
        Wq16[o * C_ + c] = bf16s(Wq[o * C_ + c]);
        acc += wk * (sc * (bsr[c] - mean[c]) + beta[c]);
    }
    for (int m = 32; m; m >>= 1) acc += __shfl_xor(acc, m);
    __shared__ float r4[4];
    if ((tid & 63) == 0) r4[tid >> 6] = acc;
    __syncthreads();
    if (tid == 0) bk[o] = r4[0] + r4[1] + r4[2] + r4[3];
}

// Wsr [co][kkold=ci*4+dy*2+dx] fp32 -> WsrT [kk'][co] bf16, kk' = (dy*2+dx)*512 + ci
__global__ __launch_bounds__(256) void k_wsrT(const float* __restrict__ Wsr, short* __restrict__ WsrT) {
    const int kt = blockIdx.x, ot = blockIdx.y;
    __shared__ float t[64][65];
    const int tid = threadIdx.x;
    {
        const int cc = tid >> 2, q = tid & 3;
        const float* xr = Wsr + (size_t)(ot * 64 + cc) * 2048 + kt * 64;
#pragma unroll
        for (int jj = 0; jj < 4; ++jj) {
            float4 f = *reinterpret_cast<const float4*>(&xr[q * 16 + jj * 4]);
            int n = q * 16 + jj * 4;
            t[n + 0][cc] = f.x; t[n + 1][cc] = f.y;
            t[n + 2][cc] = f.z; t[n + 3][cc] = f.w;
        }
    }
    __syncthreads();
    {
        const int n = tid >> 2, c0 = (tid & 3) * 16;
        bf16x8 u0, u1;
#pragma unroll
        for (int j = 0; j < 8; ++j) {
            u0[j] = bf16s(t[n][c0 + j]);
            u1[j] = bf16s(t[n][c0 + 8 + j]);
        }
        int gkk = kt * 64 + n;                      // ci-major index
        int row2 = (gkk & 3) * 512 + (gkk >> 2);    // (dy,dx)-major index kk'
        short* dst = WsrT + (size_t)row2 * C_ + ot * 64 + c0;
        *reinterpret_cast<bf16x8*>(dst) = u0;
        *reinterpret_cast<bf16x8*>(dst + 8) = u1;
    }
}

// ---------------------------------------------------------------------------
// m97-style GEMM core: acc += A[rows][K] * B[rows][K]^T (both K-contig)
// 256 thr = 4 waves (2x2). BK=64, single-buffered LDS, global_load_lds width 16.
// C row (lg*4+r) = A-dim, C col (lr) = B-dim.
template <int MT>
__device__ __forceinline__ void gemm_core(const short* __restrict__ Ag,
                                          const short* __restrict__ Bg, int K,
                                          short* Abuf, short* Bbuf,
                                          f32x4 (&acc)[MT][4]) {
    const int tid = threadIdx.x;
    const int w = tid >> 6, l = tid & 63;
    const int lr = l & 15, lg = l >> 4;
    const int wm = w >> 1, wn = w & 1;
    const int srow = tid >> 3, scol = (tid & 7) * 8;
    char* AbufC = (char*)Abuf;
    char* BbufC = (char*)Bbuf;
    for (int kt = 0; kt < K; kt += 64) {
#pragma unroll
        for (int i = 0; i < MT; ++i)
            GLD16(Ag + (size_t)(i * 32 + srow) * K + kt + scol, AbufC + i * 4096 + tid * 16);
#pragma unroll
        for (int i = 0; i < 4; ++i)
            GLD16(Bg + (size_t)(i * 32 + srow) * K + kt + scol, BbufC + i * 4096 + tid * 16);
        __syncthreads();
        bf16x8 af[MT][2], bfv[4][2];
#pragma unroll
        for (int mt = 0; mt < MT; ++mt)
#pragma unroll
            for (int ks = 0; ks < 2; ++ks)
                af[mt][ks] = *reinterpret_cast<const bf16x8*>(
                    &Abuf[(wm * MT * 16 + mt * 16 + lr) * 64 + ks * 32 + lg * 8]);
#pragma unroll
        for (int nt = 0; nt < 4; ++nt)
#pragma unroll
            for (int ks = 0; ks < 2; ++ks)
                bfv[nt][ks] = *reinterpret_cast<const bf16x8*>(
                    &Bbuf[(wn * 64 + nt * 16 + lr) * 64 + ks * 32 + lg * 8]);
#pragma unroll
        for (int mt = 0; mt < MT; ++mt)
#pragma unroll
            for (int nt = 0; nt < 4; ++nt) {
                acc[mt][nt] = __builtin_amdgcn_mfma_f32_16x16x32_bf16(af[mt][0], bfv[nt][0], acc[mt][nt], 0, 0, 0);
                acc[mt][nt] = __builtin_amdgcn_mfma_f32_16x16x32_bf16(af[mt][1], bfv[nt][1], acc[mt][nt], 0, 0, 0);
            }
        __syncthreads();
    }
}

// Wck[o][kk'] = sum_co Wk'[o,co] * WsrT[kk',co]   (M=512 BM=64, N=2048, K=512)
__global__ __launch_bounds__(256) void k_gemm_wck(const short* __restrict__ Wkp16,
                                                  const short* __restrict__ WsrT,
                                                  short* __restrict__ Wck16) {
    __shared__ short Abuf[2 * 32 * 64];
    __shared__ short Bbuf[128 * 64];
    f32x4 acc[2][4];
#pragma unroll
    for (int i = 0; i < 2; ++i)
#pragma unroll
        for (int j = 0; j < 4; ++j) acc[i][j] = (f32x4){0.f, 0.f, 0.f, 0.f};
    const int m0 = blockIdx.y * 64, n0 = blockIdx.x * 128;
    gemm_core<2>(Wkp16 + (size_t)m0 * 512, WsrT + (size_t)n0 * 512, 512, Abuf, Bbuf, acc);
    const int tid = threadIdx.x, l = tid & 63, w = tid >> 6;
    const int lr = l & 15, lg = l >> 4, wm = w >> 1, wn = w & 1;
#pragma unroll
    for (int mt = 0; mt < 2; ++mt)
#pragma unroll
        for (int nt = 0; nt < 4; ++nt) {
            int kk = n0 + wn * 64 + nt * 16 + lr;
#pragma unroll
            for (int r = 0; r < 4; ++r) {
                int o = m0 + wm * 32 + mt * 16 + lg * 4 + r;
                Wck16[(size_t)o * 2048 + kk] = bf16s(acc[mt][nt][r]);
            }
        }
}

// ---------------------------------------------------------------------------
// Fused q-GEMM + split-K k-GEMM. 768 blocks, ~equal work units.
//   bid < 256: k-partial. bid = s*128 + at*4 + wt, s = dy split.
//     kp[s][bp][o] = sum over kk' in [s*1024, s*1024+1024) of im2col*Wck
//     A = act rows (xT with row remap n = (2oy+dy)*64 + 2ox+dx), B = Wck rows.
//   bid >= 256: q2 = Wq @ x. A = Wq rows o, B = xT rows n.
__global__ __launch_bounds__(256) void k_gemm_qk2(const short* __restrict__ xT,
                                                  const short* __restrict__ Wq16,
                                                  const short* __restrict__ Wck16,
                                                  float* __restrict__ kp,
                                                  short* __restrict__ q2) {
    __shared__ short Abuf[128 * 64];
    __shared__ short Bbuf[128 * 64];
    f32x4 acc[4][4];
#pragma unroll
    for (int i = 0; i < 4; ++i)
#pragma unroll
        for (int j = 0; j < 4; ++j) acc[i][j] = (f32x4){0.f, 0.f, 0.f, 0.f};
    const int bid = blockIdx.x;
    const int tid = threadIdx.x, l = tid & 63, w = tid >> 6;
    const int lr = l & 15, lg = l >> 4, wm = w >> 1, wn = w & 1;
    const int srow = tid >> 3, scol = (tid & 7) * 8;
    char* AbufC = (char*)Abuf;
    char* BbufC = (char*)Bbuf;

    if (bid < 256) {
        const int s = bid >> 7;            // dy
        const int r2 = bid & 127;
        const int n0 = (r2 >> 2) * 128;    // act tile (bp)
        const int m0 = (r2 & 3) * 128;     // weight tile (o)
        for (int kt2 = 0; kt2 < 1024; kt2 += 64) {
            const int dx = kt2 >> 9, cc = kt2 & 511;
#pragma unroll
            for (int i = 0; i < 4; ++i) {
                int bp = n0 + i * 32 + srow;
                int b = bp >> 10, p = bp & 1023;
                int n = ((p >> 5) * 2 + s) * 64 + (p & 31) * 2 + dx;
                GLD16(xT + ((size_t)(b * N_ + n)) * C_ + cc + scol, AbufC + i * 4096 + tid * 16);
            }
#pragma unroll
            for (int i = 0; i < 4; ++i)
                GLD16(Wck16 + (size_t)(m0 + i * 32 + srow) * 2048 + s * 1024 + kt2 + scol,
                      BbufC + i * 4096 + tid * 16);
            __syncthreads();
            bf16x8 af[4][2], bfv[4][2];
#pragma unroll
            for (int mt = 0; mt < 4; ++mt)
#pragma unroll
                for (int ks = 0; ks < 2; ++ks)
                    af[mt][ks] = *reinterpret_cast<const bf16x8*>(
                        &Abuf[(wm * 64 + mt * 16 + lr) * 64 + ks * 32 + lg * 8]);
#pragma unroll
            for (int nt = 0; nt < 4; ++nt)
#pragma unroll
                for (int ks = 0; ks < 2; ++ks)
                    bfv[nt][ks] = *reinterpret_cast<const bf16x8*>(
                        &Bbuf[(wn * 64 + nt * 16 + lr) * 64 + ks * 32 + lg * 8]);
#pragma unroll
            for (int mt = 0; mt < 4; ++mt)
#pragma unroll
                for (int nt = 0; nt < 4; ++nt) {
                    acc[mt][nt] = __builtin_amdgcn_mfma_f32_16x16x32_bf16(af[mt][0], bfv[nt][0], acc[mt][nt], 0, 0, 0);
                    acc[mt][nt] = __builtin_amdgcn_mfma_f32_16x16x32_bf16(af[mt][1], bfv[nt][1], acc[mt][nt], 0, 0, 0);
                }
            __syncthreads();
        }
        float* kps = kp + (size_t)s * (4096 * 512);
#pragma unroll
        for (int mt = 0; mt < 4; ++mt)
#pragma unroll
            for (int nt = 0; nt < 4; ++nt) {
                int o = m0 + wn * 64 + nt * 16 + lr;
#pragma unroll
                for (int r = 0; r < 4; ++r) {
                    int bp = n0 + wm * 64 + mt * 16 + lg * 4 + r;
                    kps[(size_t)bp * 512 + o] = acc[mt][nt][r];
                }
            }
    } else {
        const int bq = bid - 256;
        const int m0 = (bq & 3) * 128, n0 = (bq >> 2) * 128;
        gemm_core<4>(Wq16 + (size_t)m0 * 512, xT + (size_t)n0 * 512, 512, Abuf, Bbuf, acc);
#pragma unroll
        for (int mt = 0; mt < 4; ++mt) {
            const int o0 = m0 + wm * 64 + mt * 16 + lg * 4;
            const int h = o0 >> 6, d0 = o0 & 63;
#pragma unroll
            for (int nt = 0; nt < 4; ++nt) {
                int ng = n0 + wn * 64 + nt * 16 + lr;
                int b = ng >> 12, n = ng & 4095;
                short4 u;
                u.x = bf16s(acc[mt][nt][0]);
                u.y = bf16s(acc[mt][nt][1]);
                u.z = bf16s(acc[mt][nt][2]);
                u.w = bf16s(acc[mt][nt][3]);
                *reinterpret_cast<short4*>(&q2[(((size_t)(b * NH_ + h)) * N_ + n) * HD_ + d0]) = u;
            }
        }
    }
}

// k3[b,h,p,d] = bf16( kp[0][bp][o] + kp[1][bp][o] + bk[o] )
__global__ __launch_bounds__(256) void k_kred(const float* __restrict__ kp,
                                              const float* __restrict__ bk,
                                              short* __restrict__ k3) {
    const int bp = blockIdx.x, b = bp >> 10, p = bp & 1023;
    const int o = threadIdx.x * 2;
    const float* k0 = kp + (size_t)bp * 512 + o;
    float2 s0 = *reinterpret_cast<const float2*>(k0);
    float2 s1 = *reinterpret_cast<const float2*>(k0 + (size_t)4096 * 512);
    float2 bb = *reinterpret_cast<const float2*>(&bk[o]);
    short2 u;
    u.x = bf16s(s0.x + s1.x + bb.x);
    u.y = bf16s(s0.y + s1.y + bb.y);
    const int h = o >> 6, d = o & 63;
    *reinterpret_cast<short2*>(&k3[(((size_t)(b * NH_ + h)) * NK + p) * HD_ + d]) = u;
}

// ---------------------------------------------------------------------------
// attention: am[b,h,n] = SCALE * max_p sum_d q[n,d]*k[p,d]
// A = k3 (rows p), B = q2 (cols n). Block: 128 n, 4 waves split 1024 p.
__global__ __launch_bounds__(256) void k_attn2(const short* __restrict__ k3,
                                               const short* __restrict__ q2,
                                               float* __restrict__ am) {
    const int b = blockIdx.z, h = blockIdx.y, n0 = blockIdx.x * 128;
    const int w = threadIdx.x >> 6, l = threadIdx.x & 63;
    const int lr = l & 15, lg = l >> 4;
    const short* qb = q2 + ((size_t)(b * NH_ + h)) * N_ * HD_;
    const short* kb = k3 + ((size_t)(b * NH_ + h)) * NK * HD_;

    bf16x8 bq[8][2];
#pragma unroll
    for (int nt = 0; nt < 8; ++nt)
#pragma unroll
        for (int ks = 0; ks < 2; ++ks)
            bq[nt][ks] = *reinterpret_cast<const bf16x8*>(
                &qb[(size_t)(n0 + nt * 16 + lr) * HD_ + ks * 32 + lg * 8]);

    float rmax[8];
#pragma unroll
    for (int nt = 0; nt < 8; ++nt) rmax[nt] = -3.4e38f;

    const short* kw = kb + (size_t)(w * 256) * HD_;
    const short* s0 = kw + (size_t)lr * HD_ + lg * 8;
    bf16x8 a0 = *reinterpret_cast<const bf16x8*>(s0);
    bf16x8 a1 = *reinterpret_cast<const bf16x8*>(s0 + 32);
    for (int t = 0; t < 16; ++t) {
        bf16x8 c0 = a0, c1 = a1;
        if (t < 15) {
            const short* s2 = kw + (size_t)((t + 1) * 16 + lr) * HD_ + lg * 8;
            a0 = *reinterpret_cast<const bf16x8*>(s2);
            a1 = *reinterpret_cast<const bf16x8*>(s2 + 32);
        }
#pragma unroll
        for (int nt = 0; nt < 8; ++nt) {
            f32x4 acc = {0.f, 0.f, 0.f, 0.f};
            acc = __builtin_amdgcn_mfma_f32_16x16x32_bf16(c0, bq[nt][0], acc, 0, 0, 0);
            acc = __builtin_amdgcn_mfma_f32_16x16x32_bf16(c1, bq[nt][1], acc, 0, 0, 0);
            float m = fmaxf(fmaxf(acc[0], acc[1]), fmaxf(acc[2], acc[3]));
            rmax[nt] = fmaxf(rmax[nt], m);
        }
    }
#pragma unroll
    for (int nt = 0; nt < 8; ++nt) {
        float m = rmax[nt];
        m = fmaxf(m, __shfl_xor(m, 16));
        m = fmaxf(m, __shfl_xor(m, 32));
        rmax[nt] = m;
    }
    __shared__ float sm[4][128];
    if (lg == 0) {
#pragma unroll
        for (int nt = 0; nt < 8; ++nt) sm[w][nt * 16 + lr] = rmax[nt];
    }
    __syncthreads();
    if (threadIdx.x < 128) {
        float m = fmaxf(fmaxf(sm[0][threadIdx.x], sm[1][threadIdx.x]),
                        fmaxf(sm[2][threadIdx.x], sm[3][threadIdx.x]));
        am[((size_t)(b * NH_ + h)) * N_ + n0 + threadIdx.x] = SCALE * m;
    }
}

// ---------------------------------------------------------------------------
// pv[b,o] = sum_c Wproj[o,c] * v[b,c]
__global__ void k_pv(const float* __restrict__ Wproj, const float* __restrict__ v,
                     float* __restrict__ pv) {
    int idx = blockIdx.x * 4 + (threadIdx.x >> 6);
    int lane = threadIdx.x & 63;
    int b = idx / C_, o = idx % C_;
    float s = 0.f;
    for (int c = lane; c < C_; c += 64) s += Wproj[o * C_ + c] * v[b * C_ + c];
    for (int m = 32; m; m >>= 1) s += __shfl_xor(s, m);
    if (lane == 0) pv[idx] = s;
}

// out[b,o,n] = pv[b,o] * (sum_h am[b,h,n]) + bproj[o]
__global__ void k_final(const float* __restrict__ pv, const float* __restrict__ am,
                        const float* __restrict__ bproj, float* __restrict__ out) {
    const int b = blockIdx.z, o0 = blockIdx.y * 64;
    const int n = blockIdx.x * 1024 + threadIdx.x * 4;
    float4 s = {0.f, 0.f, 0.f, 0.f};
#pragma unroll
    for (int h = 0; h < NH_; ++h) {
        float4 a = *reinterpret_cast<const float4*>(&am[((size_t)(b * NH_ + h)) * N_ + n]);
        s.x += a.x; s.y += a.y; s.z += a.z; s.w += a.w;
    }
    float* ob = out + (size_t)b * C_ * N_ + n;
    const float* pvb = pv + b * C_;
#pragma unroll 4
    for (int o = o0; o < o0 + 64; ++o) {
        float p = pvb[o], bp = bproj[o];
        float4 r = {p * s.x + bp, p * s.y + bp, p * s.z + bp, p * s.w + bp};
        *reinterpret_cast<float4*>(&ob[(size_t)o * N_]) = r;
    }
}

// ---------------------------------------------------------------------------
extern "C" void kernel_launch(void* const* d_in, const int* in_sizes, int n_in,
                              void* d_out, int out_size, void* d_ws, size_t ws_size,
                              hipStream_t stream) {
    const float* x     = (const float*)d_in[0];
    const float* Wq    = (const float*)d_in[2];
    const float* Wk    = (const float*)d_in[3];
    const float* Wsr   = (const float*)d_in[4];
    const float* bsr   = (const float*)d_in[5];
    const float* gamma = (const float*)d_in[6];
    const float* beta  = (const float*)d_in[7];
    const float* mean  = (const float*)d_in[8];
    const float* var   = (const float*)d_in[9];
    const float* Wproj = (const float*)d_in[10];
    const float* bproj = (const float*)d_in[11];
    float* out = (float*)d_out;

    char* ws = (char*)d_ws;
    // layout: 60,313,600 bytes total (== round-4 proven-available size)
    float* v     = (float*)(ws + 0);         // 8 KB
    float* pv    = (float*)(ws + 8192);      // 8 KB
    float* bk    = (float*)(ws + 16384);     // 4 KB
    float* am    = (float*)(ws + 20480);     // 512 KB
    short* Wq16  = (short*)(ws + 544768);    // 512 KB
    short* Wkp16 = (short*)(ws + 1069056);   // 512 KB
    short* WsrT  = (short*)(ws + 1593344);   // 2 MB   [kk'][co] bf16
    short* Wck16 = (short*)(ws + 3690496);   // 2 MB   [o][kk'] bf16
    short* xT    = (short*)(ws + 5787648);   // 16 MB  [b,n,c] bf16
    short* q2    = (short*)(ws + 22564864);  // 16 MB  [b,h,n,d] bf16
    short* k3    = (short*)(ws + 39342080);  // 4 MB   [b,h,p,d] bf16
    float* kp    = (float*)(ws + 43536384);  // 16 MB  [2][4096][512] fp32

    hipMemsetAsync(v, 0, B_ * C_ * sizeof(float), stream);
    k_xprep<<<dim3(64, 8, B_), 256, 0, stream>>>(x, xT, v);
    k_wprep<<<dim3(512), 256, 0, stream>>>(Wq, Wk, gamma, beta, mean, var, bsr, Wq16, Wkp16, bk);
    k_wsrT<<<dim3(32, 8), 256, 0, stream>>>(Wsr, WsrT);
    k_gemm_wck<<<dim3(16, 8), 256, 0, stream>>>(Wkp16, WsrT, Wck16);
    k_gemm_qk2<<<dim3(768), 256, 0, stream>>>(xT, Wq16, Wck16, kp, q2);
    k_kred<<<dim3(B_ * NK), 256, 0, stream>>>(kp, bk, k3);
    k_attn2<<<dim3(32, NH_, B_), 256, 0, stream>>>(k3, q2, am);
    k_pv<<<dim3(B_ * C_ / 4), 256, 0, stream>>>(Wproj, v, pv);
    k_final<<<dim3(4, 8, B_), 256, 0, stream>>>(pv, am, bproj, out);
}

// Round 6
// 117.896 us; speedup vs baseline: 4.6041x; 1.0079x over previous
//
#include <hip/hip_runtime.h>
#include <hip/hip_bf16.h>

// Problem constants (fixed by reference setup_inputs)
constexpr int B_ = 4, C_ = 512, N_ = 4096, NH_ = 8, HD_ = 64;
constexpr int NK = 1024;            // (64/2)*(64/2)
constexpr float SCALE = 0.125f;     // HD^-0.5
constexpr float EPS = 1e-5f;

typedef __attribute__((ext_vector_type(8))) short bf16x8;
typedef __attribute__((ext_vector_type(4))) float f32x4;

__device__ __forceinline__ short bf16s(float f) {
    __hip_bfloat16 h = __float2bfloat16(f);
    return *reinterpret_cast<short*>(&h);
}

#define GLD16(gp, lp)                                                                     \
    __builtin_amdgcn_global_load_lds((const __attribute__((address_space(1))) void*)(gp), \
                                     (__attribute__((address_space(3))) void*)(lp), 16, 0, 0)

// ---------------------------------------------------------------------------
// x [b,c,n] fp32 -> xT [b,n,c] bf16 ; vpart[y][b][c] = sum over this y-tile's 64 n
__global__ __launch_bounds__(256) void k_xprep(const float* __restrict__ x,
                                               short* __restrict__ xT,
                                               float* __restrict__ vpart) {
    const int b = blockIdx.z, ct = blockIdx.y, y = blockIdx.x;  // y = image row = n-tile
    __shared__ float t[64][65];
    const int tid = threadIdx.x;
    {
        const int cc = tid >> 2, q = tid & 3;
        const float* xr = x + ((size_t)(b * C_ + ct * 64 + cc)) * N_ + y * 64;
        float s = 0.f;
#pragma unroll
        for (int jj = 0; jj < 4; ++jj) {
            float4 f = *reinterpret_cast<const float4*>(&xr[q * 16 + jj * 4]);
            int n = q * 16 + jj * 4;
            t[n + 0][cc] = f.x; t[n + 1][cc] = f.y;
            t[n + 2][cc] = f.z; t[n + 3][cc] = f.w;
            s += f.x + f.y + f.z + f.w;
        }
        s += __shfl_xor(s, 1);
        s += __shfl_xor(s, 2);
        if (q == 0) vpart[((size_t)(y * B_ + b)) * C_ + ct * 64 + cc] = s;
    }
    __syncthreads();
    {   // xT [b][n][c] write (coalesced 128B per row)
        const int n = tid >> 2, c0 = (tid & 3) * 16;
        bf16x8 u0, u1;
#pragma unroll
        for (int j = 0; j < 8; ++j) {
            u0[j] = bf16s(t[n][c0 + j]);
            u1[j] = bf16s(t[n][c0 + 8 + j]);
        }
        short* dst = xT + ((size_t)(b * N_ + y * 64 + n)) * C_ + ct * 64 + c0;
        *reinterpret_cast<bf16x8*>(dst) = u0;
        *reinterpret_cast<bf16x8*>(dst + 8) = u1;
    }
}

// ---------------------------------------------------------------------------
// Merged weight prep (one dispatch):
//   bid < 512 : Wq->bf16; Wk' = Wk*s (bf16); bk[o]
//   bid >= 512: Wsr [co][ci*4+dy*2+dx] fp32 -> WsrT [kk'][co] bf16, kk'=(dy*2+dx)*512+ci
__global__ __launch_bounds__(256) void k_wprep2(const float* __restrict__ Wq, const float* __restrict__ Wk,
                                                const float* __restrict__ gamma, const float* __restrict__ beta,
                                                const float* __restrict__ mean, const float* __restrict__ var,
                                                const float* __restrict__ bsr, const float* __restrict__ Wsr,
                                                short* __restrict__ Wq16, short* __restrict__ Wkp16,
                                                float* __restrict__ bk, short* __restrict__ WsrT) {
    const int bid = blockIdx.x, tid = threadIdx.x;
    __shared__ float t[64][65];
    if (bid < 512) {
        const int o = bid;
        float acc = 0.f;
        for (int c = tid; c < C_; c += 256) {
            float sc = rsqrtf(var[c] + EPS) * gamma[c];
            float wk = Wk[o * C_ + c];
            Wkp16[o * C_ + c] = bf16s(wk * sc);
            Wq16[o * C_ + c] = bf16s(Wq[o * C_ + c]);
            acc += wk * (sc * (bsr[c] - mean[c]) + beta[c]);
        }
        for (int m = 32; m; m >>= 1) acc += __shfl_xor(acc, m);
        if ((tid & 63) == 0) t[0][tid >> 6] = acc;
        __syncthreads();
        if (tid == 0) bk[o] = t[0][0] + t[0][1] + t[0][2] + t[0][3];
    } else {
        const int kt = (bid - 512) & 31, ot = (bid - 512) >> 5;
        {
            const int cc = tid >> 2, q = tid & 3;
            const float* xr = Wsr + (size_t)(ot * 64 + cc) * 2048 + kt * 64;
#pragma unroll
            for (int jj = 0; jj < 4; ++jj) {
                float4 f = *reinterpret_cast<const float4*>(&xr[q * 16 + jj * 4]);
                int n = q * 16 + jj * 4;
                t[n + 0][cc] = f.x; t[n + 1][cc] = f.y;
                t[n + 2][cc] = f.z; t[n + 3][cc] = f.w;
            }
        }
        __syncthreads();
        {
            const int n = tid >> 2, c0 = (tid & 3) * 16;
            bf16x8 u0, u1;
#pragma unroll
            for (int j = 0; j < 8; ++j) {
                u0[j] = bf16s(t[n][c0 + j]);
                u1[j] = bf16s(t[n][c0 + 8 + j]);
            }
            int gkk = kt * 64 + n;                      // ci-major index
            int row2 = (gkk & 3) * 512 + (gkk >> 2);    // (dy,dx)-major index kk'
            short* dst = WsrT + (size_t)row2 * C_ + ot * 64 + c0;
            *reinterpret_cast<bf16x8*>(dst) = u0;
            *reinterpret_cast<bf16x8*>(dst + 8) = u1;
        }
    }
}

// ---------------------------------------------------------------------------
// m97-style GEMM core: acc += A[rows][K] * B[rows][K]^T (both K-contig)
// 256 thr = 4 waves (2x2). BK=64, single-buffered LDS, global_load_lds width 16.
// C row (lg*4+r) = A-dim, C col (lr) = B-dim.
template <int MT>
__device__ __forceinline__ void gemm_core(const short* __restrict__ Ag,
                                          const short* __restrict__ Bg, int K,
                                          short* Abuf, short* Bbuf,
                                          f32x4 (&acc)[MT][4]) {
    const int tid = threadIdx.x;
    const int w = tid >> 6, l = tid & 63;
    const int lr = l & 15, lg = l >> 4;
    const int wm = w >> 1, wn = w & 1;
    const int srow = tid >> 3, scol = (tid & 7) * 8;
    char* AbufC = (char*)Abuf;
    char* BbufC = (char*)Bbuf;
    for (int kt = 0; kt < K; kt += 64) {
#pragma unroll
        for (int i = 0; i < MT; ++i)
            GLD16(Ag + (size_t)(i * 32 + srow) * K + kt + scol, AbufC + i * 4096 + tid * 16);
#pragma unroll
        for (int i = 0; i < 4; ++i)
            GLD16(Bg + (size_t)(i * 32 + srow) * K + kt + scol, BbufC + i * 4096 + tid * 16);
        __syncthreads();
        bf16x8 af[MT][2], bfv[4][2];
#pragma unroll
        for (int mt = 0; mt < MT; ++mt)
#pragma unroll
            for (int ks = 0; ks < 2; ++ks)
                af[mt][ks] = *reinterpret_cast<const bf16x8*>(
                    &Abuf[(wm * MT * 16 + mt * 16 + lr) * 64 + ks * 32 + lg * 8]);
#pragma unroll
        for (int nt = 0; nt < 4; ++nt)
#pragma unroll
            for (int ks = 0; ks < 2; ++ks)
                bfv[nt][ks] = *reinterpret_cast<const bf16x8*>(
                    &Bbuf[(wn * 64 + nt * 16 + lr) * 64 + ks * 32 + lg * 8]);
#pragma unroll
        for (int mt = 0; mt < MT; ++mt)
#pragma unroll
            for (int nt = 0; nt < 4; ++nt) {
                acc[mt][nt] = __builtin_amdgcn_mfma_f32_16x16x32_bf16(af[mt][0], bfv[nt][0], acc[mt][nt], 0, 0, 0);
                acc[mt][nt] = __builtin_amdgcn_mfma_f32_16x16x32_bf16(af[mt][1], bfv[nt][1], acc[mt][nt], 0, 0, 0);
            }
        __syncthreads();
    }
}

// Wck[o][kk'] = sum_co Wk'[o,co] * WsrT[kk',co]   (M=512 BM=64, N=2048, K=512)
__global__ __launch_bounds__(256) void k_gemm_wck(const short* __restrict__ Wkp16,
                                                  const short* __restrict__ WsrT,
                                                  short* __restrict__ Wck16) {
    __shared__ short Abuf[2 * 32 * 64];
    __shared__ short Bbuf[128 * 64];
    f32x4 acc[2][4];
#pragma unroll
    for (int i = 0; i < 2; ++i)
#pragma unroll
        for (int j = 0; j < 4; ++j) acc[i][j] = (f32x4){0.f, 0.f, 0.f, 0.f};
    const int m0 = blockIdx.y * 64, n0 = blockIdx.x * 128;
    gemm_core<2>(Wkp16 + (size_t)m0 * 512, WsrT + (size_t)n0 * 512, 512, Abuf, Bbuf, acc);
    const int tid = threadIdx.x, l = tid & 63, w = tid >> 6;
    const int lr = l & 15, lg = l >> 4, wm = w >> 1, wn = w & 1;
#pragma unroll
    for (int mt = 0; mt < 2; ++mt)
#pragma unroll
        for (int nt = 0; nt < 4; ++nt) {
            int kk = n0 + wn * 64 + nt * 16 + lr;
#pragma unroll
            for (int r = 0; r < 4; ++r) {
                int o = m0 + wm * 32 + mt * 16 + lg * 4 + r;
                Wck16[(size_t)o * 2048 + kk] = bf16s(acc[mt][nt][r]);
            }
        }
}

// ---------------------------------------------------------------------------
// Fused q-GEMM + split-K k-GEMM. 768 blocks, ~equal work units.
//   bid < 256: k-partial. s = dy split; A = xT rows (remapped), B = Wck rows.
//   bid >= 256: q2 = Wq @ x.
__global__ __launch_bounds__(256) void k_gemm_qk2(const short* __restrict__ xT,
                                                  const short* __restrict__ Wq16,
                                                  const short* __restrict__ Wck16,
                                                  float* __restrict__ kp,
                                                  short* __restrict__ q2) {
    __shared__ short Abuf[128 * 64];
    __shared__ short Bbuf[128 * 64];
    f32x4 acc[4][4];
#pragma unroll
    for (int i = 0; i < 4; ++i)
#pragma unroll
        for (int j = 0; j < 4; ++j) acc[i][j] = (f32x4){0.f, 0.f, 0.f, 0.f};
    const int bid = blockIdx.x;
    const int tid = threadIdx.x, l = tid & 63, w = tid >> 6;
    const int lr = l & 15, lg = l >> 4, wm = w >> 1, wn = w & 1;
    const int srow = tid >> 3, scol = (tid & 7) * 8;
    char* AbufC = (char*)Abuf;
    char* BbufC = (char*)Bbuf;

    if (bid < 256) {
        const int s = bid >> 7;            // dy
        const int r2 = bid & 127;
        const int n0 = (r2 >> 2) * 128;    // act tile (bp)
        const int m0 = (r2 & 3) * 128;     // weight tile (o)
        for (int kt2 = 0; kt2 < 1024; kt2 += 64) {
            const int dx = kt2 >> 9, cc = kt2 & 511;
#pragma unroll
            for (int i = 0; i < 4; ++i) {
                int bp = n0 + i * 32 + srow;
                int b = bp >> 10, p = bp & 1023;
                int n = ((p >> 5) * 2 + s) * 64 + (p & 31) * 2 + dx;
                GLD16(xT + ((size_t)(b * N_ + n)) * C_ + cc + scol, AbufC + i * 4096 + tid * 16);
            }
#pragma unroll
            for (int i = 0; i < 4; ++i)
                GLD16(Wck16 + (size_t)(m0 + i * 32 + srow) * 2048 + s * 1024 + kt2 + scol,
                      BbufC + i * 4096 + tid * 16);
            __syncthreads();
            bf16x8 af[4][2], bfv[4][2];
#pragma unroll
            for (int mt = 0; mt < 4; ++mt)
#pragma unroll
                for (int ks = 0; ks < 2; ++ks)
                    af[mt][ks] = *reinterpret_cast<const bf16x8*>(
                        &Abuf[(wm * 64 + mt * 16 + lr) * 64 + ks * 32 + lg * 8]);
#pragma unroll
            for (int nt = 0; nt < 4; ++nt)
#pragma unroll
                for (int ks = 0; ks < 2; ++ks)
                    bfv[nt][ks] = *reinterpret_cast<const bf16x8*>(
                        &Bbuf[(wn * 64 + nt * 16 + lr) * 64 + ks * 32 + lg * 8]);
#pragma unroll
            for (int mt = 0; mt < 4; ++mt)
#pragma unroll
                for (int nt = 0; nt < 4; ++nt) {
                    acc[mt][nt] = __builtin_amdgcn_mfma_f32_16x16x32_bf16(af[mt][0], bfv[nt][0], acc[mt][nt], 0, 0, 0);
                    acc[mt][nt] = __builtin_amdgcn_mfma_f32_16x16x32_bf16(af[mt][1], bfv[nt][1], acc[mt][nt], 0, 0, 0);
                }
            __syncthreads();
        }
        float* kps = kp + (size_t)s * (4096 * 512);
#pragma unroll
        for (int mt = 0; mt < 4; ++mt)
#pragma unroll
            for (int nt = 0; nt < 4; ++nt) {
                int o = m0 + wn * 64 + nt * 16 + lr;
#pragma unroll
                for (int r = 0; r < 4; ++r) {
                    int bp = n0 + wm * 64 + mt * 16 + lg * 4 + r;
                    kps[(size_t)bp * 512 + o] = acc[mt][nt][r];
                }
            }
    } else {
        const int bq = bid - 256;
        const int m0 = (bq & 3) * 128, n0 = (bq >> 2) * 128;
        gemm_core<4>(Wq16 + (size_t)m0 * 512, xT + (size_t)n0 * 512, 512, Abuf, Bbuf, acc);
#pragma unroll
        for (int mt = 0; mt < 4; ++mt) {
            const int o0 = m0 + wm * 64 + mt * 16 + lg * 4;
            const int h = o0 >> 6, d0 = o0 & 63;
#pragma unroll
            for (int nt = 0; nt < 4; ++nt) {
                int ng = n0 + wn * 64 + nt * 16 + lr;
                int b = ng >> 12, n = ng & 4095;
                short4 u;
                u.x = bf16s(acc[mt][nt][0]);
                u.y = bf16s(acc[mt][nt][1]);
                u.z = bf16s(acc[mt][nt][2]);
                u.w = bf16s(acc[mt][nt][3]);
                *reinterpret_cast<short4*>(&q2[(((size_t)(b * NH_ + h)) * N_ + n) * HD_ + d0]) = u;
            }
        }
    }
}

// k3[b,h,p,d] = bf16( kp[0][bp][o] + kp[1][bp][o] + bk[o] )
__global__ __launch_bounds__(256) void k_kred(const float* __restrict__ kp,
                                              const float* __restrict__ bk,
                                              short* __restrict__ k3) {
    const int bp = blockIdx.x, b = bp >> 10, p = bp & 1023;
    const int o = threadIdx.x * 2;
    const float* k0 = kp + (size_t)bp * 512 + o;
    float2 s0 = *reinterpret_cast<const float2*>(k0);
    float2 s1 = *reinterpret_cast<const float2*>(k0 + (size_t)4096 * 512);
    float2 bb = *reinterpret_cast<const float2*>(&bk[o]);
    short2 u;
    u.x = bf16s(s0.x + s1.x + bb.x);
    u.y = bf16s(s0.y + s1.y + bb.y);
    const int h = o >> 6, d = o & 63;
    *reinterpret_cast<short2*>(&k3[(((size_t)(b * NH_ + h)) * NK + p) * HD_ + d]) = u;
}

// ---------------------------------------------------------------------------
// attention: am[b,h,n] = SCALE * max_p sum_d q[n,d]*k[p,d]
// A = k3 (rows p), B = q2 (cols n). Block: 128 n, 4 waves split 1024 p.
__global__ __launch_bounds__(256) void k_attn2(const short* __restrict__ k3,
                                               const short* __restrict__ q2,
                                               float* __restrict__ am) {
    const int b = blockIdx.z, h = blockIdx.y, n0 = blockIdx.x * 128;
    const int w = threadIdx.x >> 6, l = threadIdx.x & 63;
    const int lr = l & 15, lg = l >> 4;
    const short* qb = q2 + ((size_t)(b * NH_ + h)) * N_ * HD_;
    const short* kb = k3 + ((size_t)(b * NH_ + h)) * NK * HD_;

    bf16x8 bq[8][2];
#pragma unroll
    for (int nt = 0; nt < 8; ++nt)
#pragma unroll
        for (int ks = 0; ks < 2; ++ks)
            bq[nt][ks] = *reinterpret_cast<const bf16x8*>(
                &qb[(size_t)(n0 + nt * 16 + lr) * HD_ + ks * 32 + lg * 8]);

    float rmax[8];
#pragma unroll
    for (int nt = 0; nt < 8; ++nt) rmax[nt] = -3.4e38f;

    const short* kw = kb + (size_t)(w * 256) * HD_;
    const short* s0 = kw + (size_t)lr * HD_ + lg * 8;
    bf16x8 a0 = *reinterpret_cast<const bf16x8*>(s0);
    bf16x8 a1 = *reinterpret_cast<const bf16x8*>(s0 + 32);
    for (int t = 0; t < 16; ++t) {
        bf16x8 c0 = a0, c1 = a1;
        if (t < 15) {
            const short* s2 = kw + (size_t)((t + 1) * 16 + lr) * HD_ + lg * 8;
            a0 = *reinterpret_cast<const bf16x8*>(s2);
            a1 = *reinterpret_cast<const bf16x8*>(s2 + 32);
        }
        __builtin_amdgcn_s_setprio(1);
#pragma unroll
        for (int nt = 0; nt < 8; ++nt) {
            f32x4 acc = {0.f, 0.f, 0.f, 0.f};
            acc = __builtin_amdgcn_mfma_f32_16x16x32_bf16(c0, bq[nt][0], acc, 0, 0, 0);
            acc = __builtin_amdgcn_mfma_f32_16x16x32_bf16(c1, bq[nt][1], acc, 0, 0, 0);
            float m = fmaxf(fmaxf(acc[0], acc[1]), fmaxf(acc[2], acc[3]));
            rmax[nt] = fmaxf(rmax[nt], m);
        }
        __builtin_amdgcn_s_setprio(0);
    }
#pragma unroll
    for (int nt = 0; nt < 8; ++nt) {
        float m = rmax[nt];
        m = fmaxf(m, __shfl_xor(m, 16));
        m = fmaxf(m, __shfl_xor(m, 32));
        rmax[nt] = m;
    }
    __shared__ float sm[4][128];
    if (lg == 0) {
#pragma unroll
        for (int nt = 0; nt < 8; ++nt) sm[w][nt * 16 + lr] = rmax[nt];
    }
    __syncthreads();
    if (threadIdx.x < 128) {
        float m = fmaxf(fmaxf(sm[0][threadIdx.x], sm[1][threadIdx.x]),
                        fmaxf(sm[2][threadIdx.x], sm[3][threadIdx.x]));
        am[((size_t)(b * NH_ + h)) * N_ + n0 + threadIdx.x] = SCALE * m;
    }
}

// ---------------------------------------------------------------------------
// Fused v-reduce + pv: v[b,c] = (1/N) sum_y vpart[y][b][c];  pv[b,o] = sum_c Wproj[o,c]*v[b,c]
// grid (8 o-chunks, B_). Phase 1: LDS v_s; phase 2: wave-per-o dot products.
__global__ __launch_bounds__(256) void k_pvred(const float* __restrict__ vpart,
                                               const float* __restrict__ Wproj,
                                               float* __restrict__ pv) {
    const int oc = blockIdx.x, b = blockIdx.y;
    __shared__ float vs[512];
    const int tid = threadIdx.x;
    float2 s = {0.f, 0.f};
    for (int y = 0; y < 64; ++y) {
        float2 f = *reinterpret_cast<const float2*>(&vpart[((size_t)(y * B_ + b)) * C_ + tid * 2]);
        s.x += f.x; s.y += f.y;
    }
    vs[tid * 2] = s.x * (1.f / N_);
    vs[tid * 2 + 1] = s.y * (1.f / N_);
    __syncthreads();
    const int w = tid >> 6, l = tid & 63;
#pragma unroll 4
    for (int i = 0; i < 16; ++i) {
        int o = oc * 64 + i * 4 + w;
        const float* wr = Wproj + (size_t)o * C_;
        float4 a = *reinterpret_cast<const float4*>(&wr[l * 8]);
        float4 b4 = *reinterpret_cast<const float4*>(&wr[l * 8 + 4]);
        float acc = a.x * vs[l * 8] + a.y * vs[l * 8 + 1] + a.z * vs[l * 8 + 2] + a.w * vs[l * 8 + 3] +
                    b4.x * vs[l * 8 + 4] + b4.y * vs[l * 8 + 5] + b4.z * vs[l * 8 + 6] + b4.w * vs[l * 8 + 7];
        for (int m = 32; m; m >>= 1) acc += __shfl_xor(acc, m);
        if (l == 0) pv[b * C_ + o] = acc;
    }
}

// out[b,o,n] = pv[b,o] * (sum_h am[b,h,n]) + bproj[o]
__global__ void k_final(const float* __restrict__ pv, const float* __restrict__ am,
                        const float* __restrict__ bproj, float* __restrict__ out) {
    const int b = blockIdx.z, o0 = blockIdx.y * 64;
    const int n = blockIdx.x * 1024 + threadIdx.x * 4;
    float4 s = {0.f, 0.f, 0.f, 0.f};
#pragma unroll
    for (int h = 0; h < NH_; ++h) {
        float4 a = *reinterpret_cast<const float4*>(&am[((size_t)(b * NH_ + h)) * N_ + n]);
        s.x += a.x; s.y += a.y; s.z += a.z; s.w += a.w;
    }
    float* ob = out + (size_t)b * C_ * N_ + n;
    const float* pvb = pv + b * C_;
#pragma unroll 4
    for (int o = o0; o < o0 + 64; ++o) {
        float p = pvb[o], bp = bproj[o];
        float4 r = {p * s.x + bp, p * s.y + bp, p * s.z + bp, p * s.w + bp};
        *reinterpret_cast<float4*>(&ob[(size_t)o * N_]) = r;
    }
}

// ---------------------------------------------------------------------------
extern "C" void kernel_launch(void* const* d_in, const int* in_sizes, int n_in,
                              void* d_out, int out_size, void* d_ws, size_t ws_size,
                              hipStream_t stream) {
    const float* x     = (const float*)d_in[0];
    const float* Wq    = (const float*)d_in[2];
    const float* Wk    = (const float*)d_in[3];
    const float* Wsr   = (const float*)d_in[4];
    const float* bsr   = (const float*)d_in[5];
    const float* gamma = (const float*)d_in[6];
    const float* beta  = (const float*)d_in[7];
    const float* mean  = (const float*)d_in[8];
    const float* var   = (const float*)d_in[9];
    const float* Wproj = (const float*)d_in[10];
    const float* bproj = (const float*)d_in[11];
    float* out = (float*)d_out;

    char* ws = (char*)d_ws;
    // layout: ~58 MB total (within proven 60.3 MB / 256 MiB ws)
    float* vpart = (float*)(ws + 0);         // 512 KB [64][B][C]
    float* pv    = (float*)(ws + 524288);    // 8 KB
    float* bk    = (float*)(ws + 532480);    // 4 KB
    float* am    = (float*)(ws + 536576);    // 512 KB
    short* Wq16  = (short*)(ws + 1060864);   // 512 KB
    short* Wkp16 = (short*)(ws + 1585152);   // 512 KB
    short* WsrT  = (short*)(ws + 2109440);   // 2 MB   [kk'][co] bf16
    short* Wck16 = (short*)(ws + 4206592);   // 2 MB   [o][kk'] bf16
    short* xT    = (short*)(ws + 6303744);   // 16 MB  [b,n,c] bf16
    short* q2    = (short*)(ws + 23080960);  // 16 MB  [b,h,n,d] bf16
    short* k3    = (short*)(ws + 39858176);  // 4 MB   [b,h,p,d] bf16
    float* kp    = (float*)(ws + 44052480);  // 16 MB  [2][4096][512] fp32

    k_xprep<<<dim3(64, 8, B_), 256, 0, stream>>>(x, xT, vpart);
    k_wprep2<<<dim3(768), 256, 0, stream>>>(Wq, Wk, gamma, beta, mean, var, bsr, Wsr,
                                            Wq16, Wkp16, bk, WsrT);
    k_gemm_wck<<<dim3(16, 8), 256, 0, stream>>>(Wkp16, WsrT, Wck16);
    k_gemm_qk2<<<dim3(768), 256, 0, stream>>>(xT, Wq16, Wck16, kp, q2);
    k_kred<<<dim3(B_ * NK), 256, 0, stream>>>(kp, bk, k3);
    k_attn2<<<dim3(32, NH_, B_), 256, 0, stream>>>(k3, q2, am);
    k_pvred<<<dim3(8, B_), 256, 0, stream>>>(vpart, Wproj, pv);
    k_final<<<dim3(4, 8, B_), 256, 0, stream>>>(pv, am, bproj, out);
}

// Round 7
// 107.421 us; speedup vs baseline: 5.0531x; 1.0975x over previous
//
#include <hip/hip_runtime.h>
#include <hip/hip_bf16.h>

// Problem constants (fixed by reference setup_inputs)
constexpr int B_ = 4, C_ = 512, N_ = 4096, NH_ = 8, HD_ = 64;
constexpr int NK = 1024;            // (64/2)*(64/2)
constexpr float SCALE = 0.125f;     // HD^-0.5
constexpr float EPS = 1e-5f;

typedef __attribute__((ext_vector_type(8))) short bf16x8;
typedef __attribute__((ext_vector_type(4))) float f32x4;

__device__ __forceinline__ short bf16s(float f) {
    __hip_bfloat16 h = __float2bfloat16(f);
    return *reinterpret_cast<short*>(&h);
}
__device__ __forceinline__ float bf2f(short s) {
    return __bfloat162float(*reinterpret_cast<__hip_bfloat16*>(&s));
}

#define GLD16(gp, lp)                                                                     \
    __builtin_amdgcn_global_load_lds((const __attribute__((address_space(1))) void*)(gp), \
                                     (__attribute__((address_space(3))) void*)(lp), 16, 0, 0)

// ---------------------------------------------------------------------------
// P1 merged: xprep (2048 blocks) | wprep (512) | wsrT (256)
//  xprep: x [b,c,n] fp32 -> xT [b,n,c] bf16 ; vpart[y][b][c] partial sums
//  wprep: Wq->bf16; Wk' = Wk*s; bk[o]
//  wsrT : Wsr -> WsrT [kk'][co] bf16, kk' = (dy*2+dx)*512 + ci
__global__ __launch_bounds__(256) void k_xw(const float* __restrict__ x,
                                            const float* __restrict__ Wq, const float* __restrict__ Wk,
                                            const float* __restrict__ gamma, const float* __restrict__ beta,
                                            const float* __restrict__ mean, const float* __restrict__ var,
                                            const float* __restrict__ bsr, const float* __restrict__ Wsr,
                                            short* __restrict__ xT, float* __restrict__ vpart,
                                            short* __restrict__ Wq16, short* __restrict__ Wkp16,
                                            float* __restrict__ bk, short* __restrict__ WsrT) {
    const int bid = blockIdx.x, tid = threadIdx.x;
    __shared__ float t[64][65];
    if (bid < 2048) {
        const int y = bid & 63, ct = (bid >> 6) & 7, b = bid >> 9;
        {
            const int cc = tid >> 2, q = tid & 3;
            const float* xr = x + ((size_t)(b * C_ + ct * 64 + cc)) * N_ + y * 64;
            float s = 0.f;
#pragma unroll
            for (int jj = 0; jj < 4; ++jj) {
                float4 f = *reinterpret_cast<const float4*>(&xr[q * 16 + jj * 4]);
                int n = q * 16 + jj * 4;
                t[n + 0][cc] = f.x; t[n + 1][cc] = f.y;
                t[n + 2][cc] = f.z; t[n + 3][cc] = f.w;
                s += f.x + f.y + f.z + f.w;
            }
            s += __shfl_xor(s, 1);
            s += __shfl_xor(s, 2);
            if (q == 0) vpart[((size_t)(y * B_ + b)) * C_ + ct * 64 + cc] = s;
        }
        __syncthreads();
        {
            const int n = tid >> 2, c0 = (tid & 3) * 16;
            bf16x8 u0, u1;
#pragma unroll
            for (int j = 0; j < 8; ++j) {
                u0[j] = bf16s(t[n][c0 + j]);
                u1[j] = bf16s(t[n][c0 + 8 + j]);
            }
            short* dst = xT + ((size_t)(b * N_ + y * 64 + n)) * C_ + ct * 64 + c0;
            *reinterpret_cast<bf16x8*>(dst) = u0;
            *reinterpret_cast<bf16x8*>(dst + 8) = u1;
        }
    } else if (bid < 2560) {
        const int o = bid - 2048;
        float acc = 0.f;
        for (int c = tid; c < C_; c += 256) {
            float sc = rsqrtf(var[c] + EPS) * gamma[c];
            float wk = Wk[o * C_ + c];
            Wkp16[o * C_ + c] = bf16s(wk * sc);
            Wq16[o * C_ + c] = bf16s(Wq[o * C_ + c]);
            acc += wk * (sc * (bsr[c] - mean[c]) + beta[c]);
        }
        for (int m = 32; m; m >>= 1) acc += __shfl_xor(acc, m);
        if ((tid & 63) == 0) t[0][tid >> 6] = acc;
        __syncthreads();
        if (tid == 0) bk[o] = t[0][0] + t[0][1] + t[0][2] + t[0][3];
    } else {
        const int r = bid - 2560, kt = r & 31, ot = r >> 5;
        {
            const int cc = tid >> 2, q = tid & 3;
            const float* xr = Wsr + (size_t)(ot * 64 + cc) * 2048 + kt * 64;
#pragma unroll
            for (int jj = 0; jj < 4; ++jj) {
                float4 f = *reinterpret_cast<const float4*>(&xr[q * 16 + jj * 4]);
                int n = q * 16 + jj * 4;
                t[n + 0][cc] = f.x; t[n + 1][cc] = f.y;
                t[n + 2][cc] = f.z; t[n + 3][cc] = f.w;
            }
        }
        __syncthreads();
        {
            const int n = tid >> 2, c0 = (tid & 3) * 16;
            bf16x8 u0, u1;
#pragma unroll
            for (int j = 0; j < 8; ++j) {
                u0[j] = bf16s(t[n][c0 + j]);
                u1[j] = bf16s(t[n][c0 + 8 + j]);
            }
            int gkk = kt * 64 + n;                      // ci-major index
            int row2 = (gkk & 3) * 512 + (gkk >> 2);    // (dy,dx)-major index kk'
            short* dst = WsrT + (size_t)row2 * C_ + ot * 64 + c0;
            *reinterpret_cast<bf16x8*>(dst) = u0;
            *reinterpret_cast<bf16x8*>(dst + 8) = u1;
        }
    }
}

// ---------------------------------------------------------------------------
// m97-style GEMM core: acc += A[rows][K] * B[rows][K]^T (both K-contig)
// 256 thr = 4 waves (2x2). BK=64, single-buffered LDS, global_load_lds width 16.
// C row (lg*4+r) = A-dim, C col (lr) = B-dim.
template <int MT>
__device__ __forceinline__ void gemm_core(const short* __restrict__ Ag,
                                          const short* __restrict__ Bg, int K,
                                          short* Abuf, short* Bbuf,
                                          f32x4 (&acc)[MT][4]) {
    const int tid = threadIdx.x;
    const int w = tid >> 6, l = tid & 63;
    const int lr = l & 15, lg = l >> 4;
    const int wm = w >> 1, wn = w & 1;
    const int srow = tid >> 3, scol = (tid & 7) * 8;
    char* AbufC = (char*)Abuf;
    char* BbufC = (char*)Bbuf;
    for (int kt = 0; kt < K; kt += 64) {
#pragma unroll
        for (int i = 0; i < MT; ++i)
            GLD16(Ag + (size_t)(i * 32 + srow) * K + kt + scol, AbufC + i * 4096 + tid * 16);
#pragma unroll
        for (int i = 0; i < 4; ++i)
            GLD16(Bg + (size_t)(i * 32 + srow) * K + kt + scol, BbufC + i * 4096 + tid * 16);
        __syncthreads();
        bf16x8 af[MT][2], bfv[4][2];
#pragma unroll
        for (int mt = 0; mt < MT; ++mt)
#pragma unroll
            for (int ks = 0; ks < 2; ++ks)
                af[mt][ks] = *reinterpret_cast<const bf16x8*>(
                    &Abuf[(wm * MT * 16 + mt * 16 + lr) * 64 + ks * 32 + lg * 8]);
#pragma unroll
        for (int nt = 0; nt < 4; ++nt)
#pragma unroll
            for (int ks = 0; ks < 2; ++ks)
                bfv[nt][ks] = *reinterpret_cast<const bf16x8*>(
                    &Bbuf[(wn * 64 + nt * 16 + lr) * 64 + ks * 32 + lg * 8]);
#pragma unroll
        for (int mt = 0; mt < MT; ++mt)
#pragma unroll
            for (int nt = 0; nt < 4; ++nt) {
                acc[mt][nt] = __builtin_amdgcn_mfma_f32_16x16x32_bf16(af[mt][0], bfv[nt][0], acc[mt][nt], 0, 0, 0);
                acc[mt][nt] = __builtin_amdgcn_mfma_f32_16x16x32_bf16(af[mt][1], bfv[nt][1], acc[mt][nt], 0, 0, 0);
            }
        __syncthreads();
    }
}

// Wck[o][kk'] = sum_co Wk'[o,co] * WsrT[kk',co]   (M=512 BM=64, N=2048, K=512)
__global__ __launch_bounds__(256) void k_gemm_wck(const short* __restrict__ Wkp16,
                                                  const short* __restrict__ WsrT,
                                                  short* __restrict__ Wck16) {
    __shared__ short Abuf[2 * 32 * 64];
    __shared__ short Bbuf[128 * 64];
    f32x4 acc[2][4];
#pragma unroll
    for (int i = 0; i < 2; ++i)
#pragma unroll
        for (int j = 0; j < 4; ++j) acc[i][j] = (f32x4){0.f, 0.f, 0.f, 0.f};
    const int m0 = blockIdx.y * 64, n0 = blockIdx.x * 128;
    gemm_core<2>(Wkp16 + (size_t)m0 * 512, WsrT + (size_t)n0 * 512, 512, Abuf, Bbuf, acc);
    const int tid = threadIdx.x, l = tid & 63, w = tid >> 6;
    const int lr = l & 15, lg = l >> 4, wm = w >> 1, wn = w & 1;
#pragma unroll
    for (int mt = 0; mt < 2; ++mt)
#pragma unroll
        for (int nt = 0; nt < 4; ++nt) {
            int kk = n0 + wn * 64 + nt * 16 + lr;
#pragma unroll
            for (int r = 0; r < 4; ++r) {
                int o = m0 + wm * 32 + mt * 16 + lg * 4 + r;
                Wck16[(size_t)o * 2048 + kk] = bf16s(acc[mt][nt][r]);
            }
        }
}

// ---------------------------------------------------------------------------
// Fused q-GEMM + split-K k-GEMM. 768 blocks.
//   bid < 256: k-partial -> kp (bf16). bid >= 256: q2 = Wq @ x.
__global__ __launch_bounds__(256) void k_gemm_qk2(const short* __restrict__ xT,
                                                  const short* __restrict__ Wq16,
                                                  const short* __restrict__ Wck16,
                                                  short* __restrict__ kp,
                                                  short* __restrict__ q2) {
    __shared__ short Abuf[128 * 64];
    __shared__ short Bbuf[128 * 64];
    f32x4 acc[4][4];
#pragma unroll
    for (int i = 0; i < 4; ++i)
#pragma unroll
        for (int j = 0; j < 4; ++j) acc[i][j] = (f32x4){0.f, 0.f, 0.f, 0.f};
    const int bid = blockIdx.x;
    const int tid = threadIdx.x, l = tid & 63, w = tid >> 6;
    const int lr = l & 15, lg = l >> 4, wm = w >> 1, wn = w & 1;
    const int srow = tid >> 3, scol = (tid & 7) * 8;
    char* AbufC = (char*)Abuf;
    char* BbufC = (char*)Bbuf;

    if (bid < 256) {
        const int s = bid >> 7;            // dy
        const int r2 = bid & 127;
        const int n0 = (r2 >> 2) * 128;    // act tile (bp)
        const int m0 = (r2 & 3) * 128;     // weight tile (o)
        for (int kt2 = 0; kt2 < 1024; kt2 += 64) {
            const int dx = kt2 >> 9, cc = kt2 & 511;
#pragma unroll
            for (int i = 0; i < 4; ++i) {
                int bp = n0 + i * 32 + srow;
                int b = bp >> 10, p = bp & 1023;
                int n = ((p >> 5) * 2 + s) * 64 + (p & 31) * 2 + dx;
                GLD16(xT + ((size_t)(b * N_ + n)) * C_ + cc + scol, AbufC + i * 4096 + tid * 16);
            }
#pragma unroll
            for (int i = 0; i < 4; ++i)
                GLD16(Wck16 + (size_t)(m0 + i * 32 + srow) * 2048 + s * 1024 + kt2 + scol,
                      BbufC + i * 4096 + tid * 16);
            __syncthreads();
            bf16x8 af[4][2], bfv[4][2];
#pragma unroll
            for (int mt = 0; mt < 4; ++mt)
#pragma unroll
                for (int ks = 0; ks < 2; ++ks)
                    af[mt][ks] = *reinterpret_cast<const bf16x8*>(
                        &Abuf[(wm * 64 + mt * 16 + lr) * 64 + ks * 32 + lg * 8]);
#pragma unroll
            for (int nt = 0; nt < 4; ++nt)
#pragma unroll
                for (int ks = 0; ks < 2; ++ks)
                    bfv[nt][ks] = *reinterpret_cast<const bf16x8*>(
                        &Bbuf[(wn * 64 + nt * 16 + lr) * 64 + ks * 32 + lg * 8]);
#pragma unroll
            for (int mt = 0; mt < 4; ++mt)
#pragma unroll
                for (int nt = 0; nt < 4; ++nt) {
                    acc[mt][nt] = __builtin_amdgcn_mfma_f32_16x16x32_bf16(af[mt][0], bfv[nt][0], acc[mt][nt], 0, 0, 0);
                    acc[mt][nt] = __builtin_amdgcn_mfma_f32_16x16x32_bf16(af[mt][1], bfv[nt][1], acc[mt][nt], 0, 0, 0);
                }
            __syncthreads();
        }
        short* kps = kp + (size_t)s * (4096 * 512);
#pragma unroll
        for (int mt = 0; mt < 4; ++mt)
#pragma unroll
            for (int nt = 0; nt < 4; ++nt) {
                int o = m0 + wn * 64 + nt * 16 + lr;
#pragma unroll
                for (int r = 0; r < 4; ++r) {
                    int bp = n0 + wm * 64 + mt * 16 + lg * 4 + r;
                    kps[(size_t)bp * 512 + o] = bf16s(acc[mt][nt][r]);
                }
            }
    } else {
        const int bq = bid - 256;
        const int m0 = (bq & 3) * 128, n0 = (bq >> 2) * 128;
        gemm_core<4>(Wq16 + (size_t)m0 * 512, xT + (size_t)n0 * 512, 512, Abuf, Bbuf, acc);
#pragma unroll
        for (int mt = 0; mt < 4; ++mt) {
            const int o0 = m0 + wm * 64 + mt * 16 + lg * 4;
            const int h = o0 >> 6, d0 = o0 & 63;
#pragma unroll
            for (int nt = 0; nt < 4; ++nt) {
                int ng = n0 + wn * 64 + nt * 16 + lr;
                int b = ng >> 12, n = ng & 4095;
                short4 u;
                u.x = bf16s(acc[mt][nt][0]);
                u.y = bf16s(acc[mt][nt][1]);
                u.z = bf16s(acc[mt][nt][2]);
                u.w = bf16s(acc[mt][nt][3]);
                *reinterpret_cast<short4*>(&q2[(((size_t)(b * NH_ + h)) * N_ + n) * HD_ + d0]) = u;
            }
        }
    }
}

// ---------------------------------------------------------------------------
// P4 merged: kred (4096 blocks) | pvred (32 blocks)
//  kred : k3[b,h,p,d] = bf16( kp0 + kp1 + bk )
//  pvred: v = (1/N) sum_y vpart; pv = Wproj v
__global__ __launch_bounds__(256) void k_kredpv(const short* __restrict__ kp,
                                                const float* __restrict__ bk,
                                                const float* __restrict__ vpart,
                                                const float* __restrict__ Wproj,
                                                short* __restrict__ k3,
                                                float* __restrict__ pv) {
    const int bid = blockIdx.x, tid = threadIdx.x;
    if (bid < 4096) {
        const int bp = bid, b = bp >> 10, p = bp & 1023;
        const int o = tid * 2;
        const short* k0 = kp + (size_t)bp * 512 + o;
        short2 s0 = *reinterpret_cast<const short2*>(k0);
        short2 s1 = *reinterpret_cast<const short2*>(k0 + (size_t)4096 * 512);
        float2 bb = *reinterpret_cast<const float2*>(&bk[o]);
        short2 u;
        u.x = bf16s(bf2f(s0.x) + bf2f(s1.x) + bb.x);
        u.y = bf16s(bf2f(s0.y) + bf2f(s1.y) + bb.y);
        const int h = o >> 6, d = o & 63;
        *reinterpret_cast<short2*>(&k3[(((size_t)(b * NH_ + h)) * NK + p) * HD_ + d]) = u;
    } else {
        const int r = bid - 4096, oc = r & 7, b = r >> 3;
        __shared__ float vs[512];
        float2 s = {0.f, 0.f};
        for (int y = 0; y < 64; ++y) {
            float2 f = *reinterpret_cast<const float2*>(&vpart[((size_t)(y * B_ + b)) * C_ + tid * 2]);
            s.x += f.x; s.y += f.y;
        }
        vs[tid * 2] = s.x * (1.f / N_);
        vs[tid * 2 + 1] = s.y * (1.f / N_);
        __syncthreads();
        const int w = tid >> 6, l = tid & 63;
#pragma unroll 4
        for (int i = 0; i < 16; ++i) {
            int o = oc * 64 + i * 4 + w;
            const float* wr = Wproj + (size_t)o * C_;
            float4 a = *reinterpret_cast<const float4*>(&wr[l * 8]);
            float4 b4 = *reinterpret_cast<const float4*>(&wr[l * 8 + 4]);
            float acc = a.x * vs[l * 8] + a.y * vs[l * 8 + 1] + a.z * vs[l * 8 + 2] + a.w * vs[l * 8 + 3] +
                        b4.x * vs[l * 8 + 4] + b4.y * vs[l * 8 + 5] + b4.z * vs[l * 8 + 6] + b4.w * vs[l * 8 + 7];
            for (int m = 32; m; m >>= 1) acc += __shfl_xor(acc, m);
            if (l == 0) pv[b * C_ + o] = acc;
        }
    }
}

// ---------------------------------------------------------------------------
// attention: am[b,h,n] = SCALE * max_p sum_d q[n,d]*k[p,d]
// A = k3 (rows p), B = q2 (cols n). Block: 256 n, 4 waves split 1024 p.
__global__ __launch_bounds__(256) void k_attn3(const short* __restrict__ k3,
                                               const short* __restrict__ q2,
                                               float* __restrict__ am) {
    const int b = blockIdx.z, h = blockIdx.y, n0 = blockIdx.x * 256;
    const int w = threadIdx.x >> 6, l = threadIdx.x & 63;
    const int lr = l & 15, lg = l >> 4;
    const short* qb = q2 + ((size_t)(b * NH_ + h)) * N_ * HD_;
    const short* kb = k3 + ((size_t)(b * NH_ + h)) * NK * HD_;

    bf16x8 bq[16][2];
#pragma unroll
    for (int nt = 0; nt < 16; ++nt)
#pragma unroll
        for (int ks = 0; ks < 2; ++ks)
            bq[nt][ks] = *reinterpret_cast<const bf16x8*>(
                &qb[(size_t)(n0 + nt * 16 + lr) * HD_ + ks * 32 + lg * 8]);

    float rmax[16];
#pragma unroll
    for (int nt = 0; nt < 16; ++nt) rmax[nt] = -3.4e38f;

    const short* kw = kb + (size_t)(w * 256) * HD_;
    const short* s0 = kw + (size_t)lr * HD_ + lg * 8;
    bf16x8 a0 = *reinterpret_cast<const bf16x8*>(s0);
    bf16x8 a1 = *reinterpret_cast<const bf16x8*>(s0 + 32);
    for (int t = 0; t < 16; ++t) {
        bf16x8 c0 = a0, c1 = a1;
        if (t < 15) {
            const short* s2 = kw + (size_t)((t + 1) * 16 + lr) * HD_ + lg * 8;
            a0 = *reinterpret_cast<const bf16x8*>(s2);
            a1 = *reinterpret_cast<const bf16x8*>(s2 + 32);
        }
        __builtin_amdgcn_s_setprio(1);
#pragma unroll
        for (int nt = 0; nt < 16; ++nt) {
            f32x4 acc = {0.f, 0.f, 0.f, 0.f};
            acc = __builtin_amdgcn_mfma_f32_16x16x32_bf16(c0, bq[nt][0], acc, 0, 0, 0);
            acc = __builtin_amdgcn_mfma_f32_16x16x32_bf16(c1, bq[nt][1], acc, 0, 0, 0);
            // linear chain -> clang fuses to v_max3 pairs
            rmax[nt] = fmaxf(fmaxf(fmaxf(fmaxf(acc[0], acc[1]), acc[2]), acc[3]), rmax[nt]);
        }
        __builtin_amdgcn_s_setprio(0);
    }
#pragma unroll
    for (int nt = 0; nt < 16; ++nt) {
        float m = rmax[nt];
        m = fmaxf(m, __shfl_xor(m, 16));
        m = fmaxf(m, __shfl_xor(m, 32));
        rmax[nt] = m;
    }
    __shared__ float sm[4][256];
    if (lg == 0) {
#pragma unroll
        for (int nt = 0; nt < 16; ++nt) sm[w][nt * 16 + lr] = rmax[nt];
    }
    __syncthreads();
    {
        const int tid = threadIdx.x;
        float m = fmaxf(fmaxf(sm[0][tid], sm[1][tid]),
                        fmaxf(sm[2][tid], sm[3][tid]));
        am[((size_t)(b * NH_ + h)) * N_ + n0 + tid] = SCALE * m;
    }
}

// ---------------------------------------------------------------------------
// out[b,o,n] = pv[b,o] * (sum_h am[b,h,n]) + bproj[o]   (512 blocks, 2/CU)
__global__ __launch_bounds__(256) void k_final(const float* __restrict__ pv, const float* __restrict__ am,
                                               const float* __restrict__ bproj, float* __restrict__ out) {
    const int b = blockIdx.z, o0 = blockIdx.y * 64;
    const int n = blockIdx.x * 256 + (threadIdx.x & 63) * 4;
    const int og = threadIdx.x >> 6;
    float4 s = {0.f, 0.f, 0.f, 0.f};
#pragma unroll
    for (int h = 0; h < NH_; ++h) {
        float4 a = *reinterpret_cast<const float4*>(&am[((size_t)(b * NH_ + h)) * N_ + n]);
        s.x += a.x; s.y += a.y; s.z += a.z; s.w += a.w;
    }
    float* ob = out + (size_t)b * C_ * N_ + n;
    const float* pvb = pv + b * C_;
#pragma unroll 4
    for (int i = 0; i < 16; ++i) {
        int o = o0 + og * 16 + i;
        float p = pvb[o], bp = bproj[o];
        float4 r = {p * s.x + bp, p * s.y + bp, p * s.z + bp, p * s.w + bp};
        *reinterpret_cast<float4*>(&ob[(size_t)o * N_]) = r;
    }
}

// ---------------------------------------------------------------------------
extern "C" void kernel_launch(void* const* d_in, const int* in_sizes, int n_in,
                              void* d_out, int out_size, void* d_ws, size_t ws_size,
                              hipStream_t stream) {
    const float* x     = (const float*)d_in[0];
    const float* Wq    = (const float*)d_in[2];
    const float* Wk    = (const float*)d_in[3];
    const float* Wsr   = (const float*)d_in[4];
    const float* bsr   = (const float*)d_in[5];
    const float* gamma = (const float*)d_in[6];
    const float* beta  = (const float*)d_in[7];
    const float* mean  = (const float*)d_in[8];
    const float* var   = (const float*)d_in[9];
    const float* Wproj = (const float*)d_in[10];
    const float* bproj = (const float*)d_in[11];
    float* out = (float*)d_out;

    char* ws = (char*)d_ws;
    float* vpart = (float*)(ws + 0);         // 512 KB [64][B][C]
    float* pv    = (float*)(ws + 524288);    // 8 KB
    float* bk    = (float*)(ws + 532480);    // 4 KB
    float* am    = (float*)(ws + 536576);    // 512 KB
    short* Wq16  = (short*)(ws + 1060864);   // 512 KB
    short* Wkp16 = (short*)(ws + 1585152);   // 512 KB
    short* WsrT  = (short*)(ws + 2109440);   // 2 MB   [kk'][co] bf16
    short* Wck16 = (short*)(ws + 4206592);   // 2 MB   [o][kk'] bf16
    short* xT    = (short*)(ws + 6303744);   // 16 MB  [b,n,c] bf16
    short* q2    = (short*)(ws + 23080960);  // 16 MB  [b,h,n,d] bf16
    short* k3    = (short*)(ws + 39858176);  // 4 MB   [b,h,p,d] bf16
    short* kp    = (short*)(ws + 44052480);  // 8 MB   [2][4096][512] bf16

    k_xw<<<dim3(2816), 256, 0, stream>>>(x, Wq, Wk, gamma, beta, mean, var, bsr, Wsr,
                                         xT, vpart, Wq16, Wkp16, bk, WsrT);
    k_gemm_wck<<<dim3(16, 8), 256, 0, stream>>>(Wkp16, WsrT, Wck16);
    k_gemm_qk2<<<dim3(768), 256, 0, stream>>>(xT, Wq16, Wck16, kp, q2);
    k_kredpv<<<dim3(4128), 256, 0, stream>>>(kp, bk, vpart, Wproj, k3, pv);
    k_attn3<<<dim3(16, NH_, B_), 256, 0, stream>>>(k3, q2, am);
    k_final<<<dim3(16, 8, B_), 256, 0, stream>>>(pv, am, bproj, out);
}

// Round 8
// 101.822 us; speedup vs baseline: 5.3310x; 1.0550x over previous
//
#include <hip/hip_runtime.h>
#include <hip/hip_bf16.h>

// Problem constants (fixed by reference setup_inputs)
constexpr int B_ = 4, C_ = 512, N_ = 4096, NH_ = 8, HD_ = 64;
constexpr int NK = 1024;            // (64/2)*(64/2)
constexpr float SCALE = 0.125f;     // HD^-0.5
constexpr float EPS = 1e-5f;

typedef __attribute__((ext_vector_type(8))) short bf16x8;
typedef __attribute__((ext_vector_type(4))) float f32x4;

__device__ __forceinline__ short bf16s(float f) {
    __hip_bfloat16 h = __float2bfloat16(f);
    return *reinterpret_cast<short*>(&h);
}
__device__ __forceinline__ float bf2f(short s) {
    return __bfloat162float(*reinterpret_cast<__hip_bfloat16*>(&s));
}

#define GLD16(gp, lp)                                                                     \
    __builtin_amdgcn_global_load_lds((const __attribute__((address_space(1))) void*)(gp), \
                                     (__attribute__((address_space(3))) void*)(lp), 16, 0, 0)

// ---------------------------------------------------------------------------
// P1 merged: xprep (2048 blocks) | wprep (512) | wsrT (256)
__global__ __launch_bounds__(256) void k_xw(const float* __restrict__ x,
                                            const float* __restrict__ Wq, const float* __restrict__ Wk,
                                            const float* __restrict__ gamma, const float* __restrict__ beta,
                                            const float* __restrict__ mean, const float* __restrict__ var,
                                            const float* __restrict__ bsr, const float* __restrict__ Wsr,
                                            short* __restrict__ xT, float* __restrict__ vpart,
                                            short* __restrict__ Wq16, short* __restrict__ Wkp16,
                                            float* __restrict__ bk, short* __restrict__ WsrT) {
    const int bid = blockIdx.x, tid = threadIdx.x;
    __shared__ float t[64][65];
    if (bid < 2048) {
        const int y = bid & 63, ct = (bid >> 6) & 7, b = bid >> 9;
        {
            const int cc = tid >> 2, q = tid & 3;
            const float* xr = x + ((size_t)(b * C_ + ct * 64 + cc)) * N_ + y * 64;
            float s = 0.f;
#pragma unroll
            for (int jj = 0; jj < 4; ++jj) {
                float4 f = *reinterpret_cast<const float4*>(&xr[q * 16 + jj * 4]);
                int n = q * 16 + jj * 4;
                t[n + 0][cc] = f.x; t[n + 1][cc] = f.y;
                t[n + 2][cc] = f.z; t[n + 3][cc] = f.w;
                s += f.x + f.y + f.z + f.w;
            }
            s += __shfl_xor(s, 1);
            s += __shfl_xor(s, 2);
            if (q == 0) vpart[((size_t)(y * B_ + b)) * C_ + ct * 64 + cc] = s;
        }
        __syncthreads();
        {
            const int n = tid >> 2, c0 = (tid & 3) * 16;
            bf16x8 u0, u1;
#pragma unroll
            for (int j = 0; j < 8; ++j) {
                u0[j] = bf16s(t[n][c0 + j]);
                u1[j] = bf16s(t[n][c0 + 8 + j]);
            }
            short* dst = xT + ((size_t)(b * N_ + y * 64 + n)) * C_ + ct * 64 + c0;
            *reinterpret_cast<bf16x8*>(dst) = u0;
            *reinterpret_cast<bf16x8*>(dst + 8) = u1;
        }
    } else if (bid < 2560) {
        const int o = bid - 2048;
        float acc = 0.f;
        for (int c = tid; c < C_; c += 256) {
            float sc = rsqrtf(var[c] + EPS) * gamma[c];
            float wk = Wk[o * C_ + c];
            Wkp16[o * C_ + c] = bf16s(wk * sc);
            Wq16[o * C_ + c] = bf16s(Wq[o * C_ + c]);
            acc += wk * (sc * (bsr[c] - mean[c]) + beta[c]);
        }
        for (int m = 32; m; m >>= 1) acc += __shfl_xor(acc, m);
        if ((tid & 63) == 0) t[0][tid >> 6] = acc;
        __syncthreads();
        if (tid == 0) bk[o] = t[0][0] + t[0][1] + t[0][2] + t[0][3];
    } else {
        const int r = bid - 2560, kt = r & 31, ot = r >> 5;
        {
            const int cc = tid >> 2, q = tid & 3;
            const float* xr = Wsr + (size_t)(ot * 64 + cc) * 2048 + kt * 64;
#pragma unroll
            for (int jj = 0; jj < 4; ++jj) {
                float4 f = *reinterpret_cast<const float4*>(&xr[q * 16 + jj * 4]);
                int n = q * 16 + jj * 4;
                t[n + 0][cc] = f.x; t[n + 1][cc] = f.y;
                t[n + 2][cc] = f.z; t[n + 3][cc] = f.w;
            }
        }
        __syncthreads();
        {
            const int n = tid >> 2, c0 = (tid & 3) * 16;
            bf16x8 u0, u1;
#pragma unroll
            for (int j = 0; j < 8; ++j) {
                u0[j] = bf16s(t[n][c0 + j]);
                u1[j] = bf16s(t[n][c0 + 8 + j]);
            }
            int gkk = kt * 64 + n;                      // ci-major index
            int row2 = (gkk & 3) * 512 + (gkk >> 2);    // (dy,dx)-major index kk'
            short* dst = WsrT + (size_t)row2 * C_ + ot * 64 + c0;
            *reinterpret_cast<bf16x8*>(dst) = u0;
            *reinterpret_cast<bf16x8*>(dst + 8) = u1;
        }
    }
}

// ---------------------------------------------------------------------------
// m97-style GEMM core (128xBN tiles): acc += A[rows][K] * B[rows][K]^T
template <int MT>
__device__ __forceinline__ void gemm_core(const short* __restrict__ Ag,
                                          const short* __restrict__ Bg, int K,
                                          short* Abuf, short* Bbuf,
                                          f32x4 (&acc)[MT][4]) {
    const int tid = threadIdx.x;
    const int w = tid >> 6, l = tid & 63;
    const int lr = l & 15, lg = l >> 4;
    const int wm = w >> 1, wn = w & 1;
    const int srow = tid >> 3, scol = (tid & 7) * 8;
    char* AbufC = (char*)Abuf;
    char* BbufC = (char*)Bbuf;
    for (int kt = 0; kt < K; kt += 64) {
#pragma unroll
        for (int i = 0; i < MT; ++i)
            GLD16(Ag + (size_t)(i * 32 + srow) * K + kt + scol, AbufC + i * 4096 + tid * 16);
#pragma unroll
        for (int i = 0; i < 4; ++i)
            GLD16(Bg + (size_t)(i * 32 + srow) * K + kt + scol, BbufC + i * 4096 + tid * 16);
        __syncthreads();
        bf16x8 af[MT][2], bfv[4][2];
#pragma unroll
        for (int mt = 0; mt < MT; ++mt)
#pragma unroll
            for (int ks = 0; ks < 2; ++ks)
                af[mt][ks] = *reinterpret_cast<const bf16x8*>(
                    &Abuf[(wm * MT * 16 + mt * 16 + lr) * 64 + ks * 32 + lg * 8]);
#pragma unroll
        for (int nt = 0; nt < 4; ++nt)
#pragma unroll
            for (int ks = 0; ks < 2; ++ks)
                bfv[nt][ks] = *reinterpret_cast<const bf16x8*>(
                    &Bbuf[(wn * 64 + nt * 16 + lr) * 64 + ks * 32 + lg * 8]);
#pragma unroll
        for (int mt = 0; mt < MT; ++mt)
#pragma unroll
            for (int nt = 0; nt < 4; ++nt) {
                acc[mt][nt] = __builtin_amdgcn_mfma_f32_16x16x32_bf16(af[mt][0], bfv[nt][0], acc[mt][nt], 0, 0, 0);
                acc[mt][nt] = __builtin_amdgcn_mfma_f32_16x16x32_bf16(af[mt][1], bfv[nt][1], acc[mt][nt], 0, 0, 0);
            }
        __syncthreads();
    }
}

// ---------------------------------------------------------------------------
// Wck via 64x64-tile GEMM, 256 blocks (2 waves-quadrants of 32x32 each... 4 waves 2x2).
// A = WsrT rows kk' (M=2048), B = Wkp16 rows o (N=512), K=512 (co).
// C row = kk' (4 consecutive per lane) -> short4 store into Wck16[o][kk'].
__global__ __launch_bounds__(256) void k_wck64(const short* __restrict__ WsrT,
                                               const short* __restrict__ Wkp16,
                                               short* __restrict__ Wck16) {
    __shared__ short Ab[64 * 64];
    __shared__ short Bb[64 * 64];
    const int m0 = blockIdx.x * 64;   // kk'
    const int n0 = blockIdx.y * 64;   // o
    const int tid = threadIdx.x, w = tid >> 6, l = tid & 63;
    const int lr = l & 15, lg = l >> 4, wm = w >> 1, wn = w & 1;
    const int srow = tid >> 3, scol = (tid & 7) * 8;  // shorts
    f32x4 acc[2][2];
#pragma unroll
    for (int i = 0; i < 2; ++i)
#pragma unroll
        for (int j = 0; j < 2; ++j) acc[i][j] = (f32x4){0.f, 0.f, 0.f, 0.f};
    char* AbC = (char*)Ab;
    char* BbC = (char*)Bb;
    for (int kt = 0; kt < 512; kt += 64) {
#pragma unroll
        for (int j = 0; j < 2; ++j) {
            GLD16(WsrT + (size_t)(m0 + j * 32 + srow) * 512 + kt + scol, AbC + j * 4096 + tid * 16);
            GLD16(Wkp16 + (size_t)(n0 + j * 32 + srow) * 512 + kt + scol, BbC + j * 4096 + tid * 16);
        }
        __syncthreads();
        bf16x8 af[2][2], bfv[2][2];
#pragma unroll
        for (int mt = 0; mt < 2; ++mt)
#pragma unroll
            for (int ks = 0; ks < 2; ++ks)
                af[mt][ks] = *reinterpret_cast<const bf16x8*>(
                    &Ab[(wm * 32 + mt * 16 + lr) * 64 + ks * 32 + lg * 8]);
#pragma unroll
        for (int nt = 0; nt < 2; ++nt)
#pragma unroll
            for (int ks = 0; ks < 2; ++ks)
                bfv[nt][ks] = *reinterpret_cast<const bf16x8*>(
                    &Bb[(wn * 32 + nt * 16 + lr) * 64 + ks * 32 + lg * 8]);
#pragma unroll
        for (int mt = 0; mt < 2; ++mt)
#pragma unroll
            for (int nt = 0; nt < 2; ++nt) {
                acc[mt][nt] = __builtin_amdgcn_mfma_f32_16x16x32_bf16(af[mt][0], bfv[nt][0], acc[mt][nt], 0, 0, 0);
                acc[mt][nt] = __builtin_amdgcn_mfma_f32_16x16x32_bf16(af[mt][1], bfv[nt][1], acc[mt][nt], 0, 0, 0);
            }
        __syncthreads();
    }
#pragma unroll
    for (int mt = 0; mt < 2; ++mt)
#pragma unroll
        for (int nt = 0; nt < 2; ++nt) {
            int kk0 = m0 + wm * 32 + mt * 16 + lg * 4;
            int o = n0 + wn * 32 + nt * 16 + lr;
            short4 u;
            u.x = bf16s(acc[mt][nt][0]);
            u.y = bf16s(acc[mt][nt][1]);
            u.z = bf16s(acc[mt][nt][2]);
            u.w = bf16s(acc[mt][nt][3]);
            *reinterpret_cast<short4*>(&Wck16[(size_t)o * 2048 + kk0]) = u;
        }
}

// ---------------------------------------------------------------------------
// Fused q-GEMM + split-K(x4) k-GEMM. 1024 blocks, ALL units K=512 (uniform).
//   bid < 512: k-partial, s = dy*2+dx = bid>>7. A = xT rows (remapped), B = Wck rows.
//   bid >= 512: q2 = Wq @ x.
__global__ __launch_bounds__(256) void k_gemm_qk2(const short* __restrict__ xT,
                                                  const short* __restrict__ Wq16,
                                                  const short* __restrict__ Wck16,
                                                  short* __restrict__ kp,
                                                  short* __restrict__ q2) {
    __shared__ short Abuf[128 * 64];
    __shared__ short Bbuf[128 * 64];
    f32x4 acc[4][4];
#pragma unroll
    for (int i = 0; i < 4; ++i)
#pragma unroll
        for (int j = 0; j < 4; ++j) acc[i][j] = (f32x4){0.f, 0.f, 0.f, 0.f};
    const int bid = blockIdx.x;
    const int tid = threadIdx.x, l = tid & 63, w = tid >> 6;
    const int lr = l & 15, lg = l >> 4, wm = w >> 1, wn = w & 1;
    const int srow = tid >> 3, scol = (tid & 7) * 8;
    char* AbufC = (char*)Abuf;
    char* BbufC = (char*)Bbuf;

    if (bid < 512) {
        const int s = bid >> 7;            // dy*2 + dx
        const int dy = s >> 1, dx = s & 1;
        const int r2 = bid & 127;
        const int n0 = (r2 >> 2) * 128;    // act tile (bp)
        const int m0 = (r2 & 3) * 128;     // weight tile (o)
        for (int kt2 = 0; kt2 < 512; kt2 += 64) {
#pragma unroll
            for (int i = 0; i < 4; ++i) {
                int bp = n0 + i * 32 + srow;
                int b = bp >> 10, p = bp & 1023;
                int n = ((p >> 5) * 2 + dy) * 64 + (p & 31) * 2 + dx;
                GLD16(xT + ((size_t)(b * N_ + n)) * C_ + kt2 + scol, AbufC + i * 4096 + tid * 16);
            }
#pragma unroll
            for (int i = 0; i < 4; ++i)
                GLD16(Wck16 + (size_t)(m0 + i * 32 + srow) * 2048 + s * 512 + kt2 + scol,
                      BbufC + i * 4096 + tid * 16);
            __syncthreads();
            bf16x8 af[4][2], bfv[4][2];
#pragma unroll
            for (int mt = 0; mt < 4; ++mt)
#pragma unroll
                for (int ks = 0; ks < 2; ++ks)
                    af[mt][ks] = *reinterpret_cast<const bf16x8*>(
                        &Abuf[(wm * 64 + mt * 16 + lr) * 64 + ks * 32 + lg * 8]);
#pragma unroll
            for (int nt = 0; nt < 4; ++nt)
#pragma unroll
                for (int ks = 0; ks < 2; ++ks)
                    bfv[nt][ks] = *reinterpret_cast<const bf16x8*>(
                        &Bbuf[(wn * 64 + nt * 16 + lr) * 64 + ks * 32 + lg * 8]);
#pragma unroll
            for (int mt = 0; mt < 4; ++mt)
#pragma unroll
                for (int nt = 0; nt < 4; ++nt) {
                    acc[mt][nt] = __builtin_amdgcn_mfma_f32_16x16x32_bf16(af[mt][0], bfv[nt][0], acc[mt][nt], 0, 0, 0);
                    acc[mt][nt] = __builtin_amdgcn_mfma_f32_16x16x32_bf16(af[mt][1], bfv[nt][1], acc[mt][nt], 0, 0, 0);
                }
            __syncthreads();
        }
        short* kps = kp + (size_t)s * (4096 * 512);
#pragma unroll
        for (int mt = 0; mt < 4; ++mt)
#pragma unroll
            for (int nt = 0; nt < 4; ++nt) {
                int o = m0 + wn * 64 + nt * 16 + lr;
#pragma unroll
                for (int r = 0; r < 4; ++r) {
                    int bp = n0 + wm * 64 + mt * 16 + lg * 4 + r;
                    kps[(size_t)bp * 512 + o] = bf16s(acc[mt][nt][r]);
                }
            }
    } else {
        const int bq = bid - 512;
        const int m0 = (bq & 3) * 128, n0 = (bq >> 2) * 128;
        gemm_core<4>(Wq16 + (size_t)m0 * 512, xT + (size_t)n0 * 512, 512, Abuf, Bbuf, acc);
#pragma unroll
        for (int mt = 0; mt < 4; ++mt) {
            const int o0 = m0 + wm * 64 + mt * 16 + lg * 4;
            const int h = o0 >> 6, d0 = o0 & 63;
#pragma unroll
            for (int nt = 0; nt < 4; ++nt) {
                int ng = n0 + wn * 64 + nt * 16 + lr;
                int b = ng >> 12, n = ng & 4095;
                short4 u;
                u.x = bf16s(acc[mt][nt][0]);
                u.y = bf16s(acc[mt][nt][1]);
                u.z = bf16s(acc[mt][nt][2]);
                u.w = bf16s(acc[mt][nt][3]);
                *reinterpret_cast<short4*>(&q2[(((size_t)(b * NH_ + h)) * N_ + n) * HD_ + d0]) = u;
            }
        }
    }
}

// ---------------------------------------------------------------------------
// P4 merged: kred (4096 blocks, 4 partials) | pvred (32 blocks)
__global__ __launch_bounds__(256) void k_kredpv(const short* __restrict__ kp,
                                                const float* __restrict__ bk,
                                                const float* __restrict__ vpart,
                                                const float* __restrict__ Wproj,
                                                short* __restrict__ k3,
                                                float* __restrict__ pv) {
    const int bid = blockIdx.x, tid = threadIdx.x;
    if (bid < 4096) {
        const int bp = bid, b = bp >> 10, p = bp & 1023;
        const int o = tid * 2;
        const short* k0 = kp + (size_t)bp * 512 + o;
        float2 bb = *reinterpret_cast<const float2*>(&bk[o]);
        float sx = bb.x, sy = bb.y;
#pragma unroll
        for (int s = 0; s < 4; ++s) {
            short2 v2 = *reinterpret_cast<const short2*>(k0 + (size_t)s * (4096 * 512));
            sx += bf2f(v2.x);
            sy += bf2f(v2.y);
        }
        short2 u;
        u.x = bf16s(sx);
        u.y = bf16s(sy);
        const int h = o >> 6, d = o & 63;
        *reinterpret_cast<short2*>(&k3[(((size_t)(b * NH_ + h)) * NK + p) * HD_ + d]) = u;
    } else {
        const int r = bid - 4096, oc = r & 7, b = r >> 3;
        __shared__ float vs[512];
        float2 s = {0.f, 0.f};
        for (int y = 0; y < 64; ++y) {
            float2 f = *reinterpret_cast<const float2*>(&vpart[((size_t)(y * B_ + b)) * C_ + tid * 2]);
            s.x += f.x; s.y += f.y;
        }
        vs[tid * 2] = s.x * (1.f / N_);
        vs[tid * 2 + 1] = s.y * (1.f / N_);
        __syncthreads();
        const int w = tid >> 6, l = tid & 63;
#pragma unroll 4
        for (int i = 0; i < 16; ++i) {
            int o = oc * 64 + i * 4 + w;
            const float* wr = Wproj + (size_t)o * C_;
            float4 a = *reinterpret_cast<const float4*>(&wr[l * 8]);
            float4 b4 = *reinterpret_cast<const float4*>(&wr[l * 8 + 4]);
            float acc = a.x * vs[l * 8] + a.y * vs[l * 8 + 1] + a.z * vs[l * 8 + 2] + a.w * vs[l * 8 + 3] +
                        b4.x * vs[l * 8 + 4] + b4.y * vs[l * 8 + 5] + b4.z * vs[l * 8 + 6] + b4.w * vs[l * 8 + 7];
            for (int m = 32; m; m >>= 1) acc += __shfl_xor(acc, m);
            if (l == 0) pv[b * C_ + o] = acc;
        }
    }
}

// ---------------------------------------------------------------------------
// attention: am[b,h,n] = SCALE * max_p sum_d q[n,d]*k[p,d]
// A = k3 (rows p), B = q2 (cols n). Block: 256 n, 4 waves split 1024 p.
__global__ __launch_bounds__(256) void k_attn3(const short* __restrict__ k3,
                                               const short* __restrict__ q2,
                                               float* __restrict__ am) {
    const int b = blockIdx.z, h = blockIdx.y, n0 = blockIdx.x * 256;
    const int w = threadIdx.x >> 6, l = threadIdx.x & 63;
    const int lr = l & 15, lg = l >> 4;
    const short* qb = q2 + ((size_t)(b * NH_ + h)) * N_ * HD_;
    const short* kb = k3 + ((size_t)(b * NH_ + h)) * NK * HD_;

    bf16x8 bq[16][2];
#pragma unroll
    for (int nt = 0; nt < 16; ++nt)
#pragma unroll
        for (int ks = 0; ks < 2; ++ks)
            bq[nt][ks] = *reinterpret_cast<const bf16x8*>(
                &qb[(size_t)(n0 + nt * 16 + lr) * HD_ + ks * 32 + lg * 8]);

    float rmax[16];
#pragma unroll
    for (int nt = 0; nt < 16; ++nt) rmax[nt] = -3.4e38f;

    const short* kw = kb + (size_t)(w * 256) * HD_;
    const short* s0 = kw + (size_t)lr * HD_ + lg * 8;
    bf16x8 a0 = *reinterpret_cast<const bf16x8*>(s0);
    bf16x8 a1 = *reinterpret_cast<const bf16x8*>(s0 + 32);
    for (int t = 0; t < 16; ++t) {
        bf16x8 c0 = a0, c1 = a1;
        if (t < 15) {
            const short* s2 = kw + (size_t)((t + 1) * 16 + lr) * HD_ + lg * 8;
            a0 = *reinterpret_cast<const bf16x8*>(s2);
            a1 = *reinterpret_cast<const bf16x8*>(s2 + 32);
        }
        __builtin_amdgcn_s_setprio(1);
#pragma unroll
        for (int nt = 0; nt < 16; ++nt) {
            f32x4 acc = {0.f, 0.f, 0.f, 0.f};
            acc = __builtin_amdgcn_mfma_f32_16x16x32_bf16(c0, bq[nt][0], acc, 0, 0, 0);
            acc = __builtin_amdgcn_mfma_f32_16x16x32_bf16(c1, bq[nt][1], acc, 0, 0, 0);
            rmax[nt] = fmaxf(fmaxf(fmaxf(fmaxf(acc[0], acc[1]), acc[2]), acc[3]), rmax[nt]);
        }
        __builtin_amdgcn_s_setprio(0);
    }
#pragma unroll
    for (int nt = 0; nt < 16; ++nt) {
        float m = rmax[nt];
        m = fmaxf(m, __shfl_xor(m, 16));
        m = fmaxf(m, __shfl_xor(m, 32));
        rmax[nt] = m;
    }
    __shared__ float sm[4][256];
    if (lg == 0) {
#pragma unroll
        for (int nt = 0; nt < 16; ++nt) sm[w][nt * 16 + lr] = rmax[nt];
    }
    __syncthreads();
    {
        const int tid = threadIdx.x;
        float m = fmaxf(fmaxf(sm[0][tid], sm[1][tid]),
                        fmaxf(sm[2][tid], sm[3][tid]));
        am[((size_t)(b * NH_ + h)) * N_ + n0 + tid] = SCALE * m;
    }
}

// ---------------------------------------------------------------------------
// out[b,o,n] = pv[b,o] * (sum_h am[b,h,n]) + bproj[o]   (1024 blocks, 4/CU)
__global__ __launch_bounds__(256) void k_final(const float* __restrict__ pv, const float* __restrict__ am,
                                               const float* __restrict__ bproj, float* __restrict__ out) {
    const int b = blockIdx.z, o0 = blockIdx.y * 64 + (threadIdx.x >> 5) * 8;
    const int n = blockIdx.x * 128 + (threadIdx.x & 31) * 4;
    float4 s = {0.f, 0.f, 0.f, 0.f};
#pragma unroll
    for (int h = 0; h < NH_; ++h) {
        float4 a = *reinterpret_cast<const float4*>(&am[((size_t)(b * NH_ + h)) * N_ + n]);
        s.x += a.x; s.y += a.y; s.z += a.z; s.w += a.w;
    }
    float* ob = out + (size_t)b * C_ * N_ + n;
    const float* pvb = pv + b * C_;
#pragma unroll
    for (int i = 0; i < 8; ++i) {
        int o = o0 + i;
        float p = pvb[o], bp = bproj[o];
        float4 r = {p * s.x + bp, p * s.y + bp, p * s.z + bp, p * s.w + bp};
        *reinterpret_cast<float4*>(&ob[(size_t)o * N_]) = r;
    }
}

// ---------------------------------------------------------------------------
extern "C" void kernel_launch(void* const* d_in, const int* in_sizes, int n_in,
                              void* d_out, int out_size, void* d_ws, size_t ws_size,
                              hipStream_t stream) {
    const float* x     = (const float*)d_in[0];
    const float* Wq    = (const float*)d_in[2];
    const float* Wk    = (const float*)d_in[3];
    const float* Wsr   = (const float*)d_in[4];
    const float* bsr   = (const float*)d_in[5];
    const float* gamma = (const float*)d_in[6];
    const float* beta  = (const float*)d_in[7];
    const float* mean  = (const float*)d_in[8];
    const float* var   = (const float*)d_in[9];
    const float* Wproj = (const float*)d_in[10];
    const float* bproj = (const float*)d_in[11];
    float* out = (float*)d_out;

    char* ws = (char*)d_ws;
    float* vpart = (float*)(ws + 0);         // 512 KB [64][B][C]
    float* pv    = (float*)(ws + 524288);    // 8 KB
    float* bk    = (float*)(ws + 532480);    // 4 KB
    float* am    = (float*)(ws + 536576);    // 512 KB
    short* Wq16  = (short*)(ws + 1060864);   // 512 KB
    short* Wkp16 = (short*)(ws + 1585152);   // 512 KB
    short* WsrT  = (short*)(ws + 2109440);   // 2 MB   [kk'][co] bf16
    short* Wck16 = (short*)(ws + 4206592);   // 2 MB   [o][kk'] bf16
    short* xT    = (short*)(ws + 6303744);   // 16 MB  [b,n,c] bf16
    short* q2    = (short*)(ws + 23080960);  // 16 MB  [b,h,n,d] bf16
    short* k3    = (short*)(ws + 39858176);  // 4 MB   [b,h,p,d] bf16
    short* kp    = (short*)(ws + 44052480);  // 16 MB  [4][4096][512] bf16

    k_xw<<<dim3(2816), 256, 0, stream>>>(x, Wq, Wk, gamma, beta, mean, var, bsr, Wsr,
                                         xT, vpart, Wq16, Wkp16, bk, WsrT);
    k_wck64<<<dim3(32, 8), 256, 0, stream>>>(WsrT, Wkp16, Wck16);
    k_gemm_qk2<<<dim3(1024), 256, 0, stream>>>(xT, Wq16, Wck16, kp, q2);
    k_kredpv<<<dim3(4128), 256, 0, stream>>>(kp, bk, vpart, Wproj, k3, pv);
    k_attn3<<<dim3(16, NH_, B_), 256, 0, stream>>>(k3, q2, am);
    k_final<<<dim3(32, 8, B_), 256, 0, stream>>>(pv, am, bproj, out);
}